// Round 15
// baseline (545.353 us; speedup 1.0000x reference)
//
#include <hip/hip_runtime.h>
#include <hip/hip_bf16.h>

#define NPTS 2048
#define NB 4
#define KNN 32
#define NIN 33

static __device__ __forceinline__ float b2f(__hip_bfloat16 v) { return __bfloat162float(v); }
#define ISQ 0.99999499996875f /* 1/sqrt(1+1e-5) */

typedef __attribute__((ext_vector_type(8))) short short8v;   // 8 bf16 (4 VGPRs)
typedef __attribute__((ext_vector_type(4))) float f32x4;

// monotone order-preserving key for fp32 (no NaNs): a<b  <=>  ordkey(a)<ordkey(b)
static __device__ __forceinline__ unsigned ordkey(float f) {
  unsigned u = __float_as_uint(f);
  return u ^ (unsigned)(((int)u >> 31) | 0x80000000);
}

static __device__ __forceinline__ void loadv(const float* p, float (&d)[1]) { d[0] = *p; }
static __device__ __forceinline__ void loadv(const float* p, float (&d)[2]) {
  float2 v = *(const float2*)p; d[0] = v.x; d[1] = v.y;
}
static __device__ __forceinline__ void loadv(const float* p, float (&d)[4]) {
  float4 v = *(const float4*)p; d[0] = v.x; d[1] = v.y; d[2] = v.z; d[3] = v.w;
}

static __device__ __forceinline__ float wave_red_sum(float s) {
#pragma unroll
  for (int off = 32; off > 0; off >>= 1) s += __shfl_xor(s, off);
  return s;
}

// ---- dtype detect: flag=1 if buffer is bf16, 0 if fp32 ----
__global__ __launch_bounds__(64) void detect_kernel(const unsigned short* __restrict__ x,
                                                    int* __restrict__ flag) {
  int cnt = 0;
  for (int i = threadIdx.x; i < 512; i += 64) {
    unsigned e = (x[i] >> 7) & 0xFFu;
    if (e >= 0xC6u) cnt++;
  }
#pragma unroll
  for (int off = 32; off > 0; off >>= 1) cnt += __shfl_down(cnt, off);
  if (threadIdx.x == 0) flag[0] = (cnt == 0) ? 1 : 0;
}

struct CvtArgs {
  const void* src[NIN];
  int off[NIN + 1];
};

// blocks [0, nb1): convert all inputs into fp32 pool.
// blocks [nb1, nb1+2048): convert W5 to bf16.
// blocks [nb1+2048, +32): xx for layer 1 straight from raw input.
__global__ __launch_bounds__(256) void cvt_all_kernel(CvtArgs a, float* __restrict__ out,
                                                      int total, int nb1,
                                                      __hip_bfloat16* __restrict__ w5bf,
                                                      float* __restrict__ xxb,
                                                      const int* __restrict__ flag) {
  int fl = flag[0];
  if ((int)blockIdx.x < nb1) {
    int t = blockIdx.x * 256 + threadIdx.x;
    if (t >= total) return;
    int s = 0;
    while (t >= a.off[s + 1]) s++;
    int j = t - a.off[s];
    float v;
    if (fl) v = b2f(((const __hip_bfloat16*)a.src[s])[j]);
    else    v = ((const float*)a.src[s])[j];
    out[t] = v;
  } else if ((int)blockIdx.x < nb1 + 2048) {
    int t = (blockIdx.x - nb1) * 256 + threadIdx.x;   // 1024*512
    if (fl) w5bf[t] = ((const __hip_bfloat16*)a.src[15])[t];
    else    w5bf[t] = __float2bfloat16(((const float*)a.src[15])[t]);
  } else {
    int t = (blockIdx.x - nb1 - 2048) * 256 + threadIdx.x;  // b*NPTS + m (8192)
    int b = t >> 11, m = t & 2047;
    float s = 0.f;
#pragma unroll
    for (int c = 0; c < 3; ++c) {
      long o = ((long)b * 3 + c) * NPTS + m;
      float v = fl ? b2f(((const __hip_bfloat16*)a.src[0])[o])
                   : ((const float*)a.src[0])[o];
      s = fmaf(v, v, s);
    }
    xxb[t] = s;
  }
}

// ---- pd body: 64x64 symmetric tile (triangular id), LDS Ts mirror ----
template <int C>
static __device__ __forceinline__ void pd_body(char* smem, const float* __restrict__ x,
                                               long bstride, const float* __restrict__ xx,
                                               unsigned* __restrict__ keys, int t, int bb) {
  constexpr int KT = (C < 16) ? C : 16;
  float* At = (float*)smem;                  // [KT][64]
  float* Bt = At + KT * 64;                  // [KT][64]
  unsigned* Ts = (unsigned*)(Bt + KT * 64);  // [64][68]
  int tj = (int)((sqrtf(8.f * (float)t + 1.f) - 1.f) * 0.5f);
  while ((tj + 1) * (tj + 2) / 2 <= t) tj++;
  while (tj * (tj + 1) / 2 > t) tj--;
  int ti = t - tj * (tj + 1) / 2;            // ti <= tj
  int n0 = ti * 64, m0 = tj * 64;
  int tid = threadIdx.x, tx = tid & 15, ty = tid >> 4;
  const float* xb = x + (long)bb * bstride;
  float acc[4][4] = {};
  for (int k0 = 0; k0 < C; k0 += KT) {
    for (int lin = tid; lin < KT * 64; lin += 256) {
      int r = lin >> 6, col = lin & 63;
      At[r * 64 + col] = xb[(long)(k0 + r) * NPTS + n0 + col];
      Bt[r * 64 + col] = xb[(long)(k0 + r) * NPTS + m0 + col];
    }
    __syncthreads();
#pragma unroll
    for (int kc = 0; kc < KT; ++kc) {
      float4 av = *(const float4*)&At[kc * 64 + ty * 4];
      float4 bv = *(const float4*)&Bt[kc * 64 + tx * 4];
      acc[0][0] = fmaf(av.x, bv.x, acc[0][0]); acc[0][1] = fmaf(av.x, bv.y, acc[0][1]);
      acc[0][2] = fmaf(av.x, bv.z, acc[0][2]); acc[0][3] = fmaf(av.x, bv.w, acc[0][3]);
      acc[1][0] = fmaf(av.y, bv.x, acc[1][0]); acc[1][1] = fmaf(av.y, bv.y, acc[1][1]);
      acc[1][2] = fmaf(av.y, bv.z, acc[1][2]); acc[1][3] = fmaf(av.y, bv.w, acc[1][3]);
      acc[2][0] = fmaf(av.z, bv.x, acc[2][0]); acc[2][1] = fmaf(av.z, bv.y, acc[2][1]);
      acc[2][2] = fmaf(av.z, bv.z, acc[2][2]); acc[2][3] = fmaf(av.z, bv.w, acc[2][3]);
      acc[3][0] = fmaf(av.w, bv.x, acc[3][0]); acc[3][1] = fmaf(av.w, bv.y, acc[3][1]);
      acc[3][2] = fmaf(av.w, bv.z, acc[3][2]); acc[3][3] = fmaf(av.w, bv.w, acc[3][3]);
    }
    __syncthreads();
  }
  const float* xxq = xx + (long)bb * NPTS;
  float4 xxm = *(const float4*)&xxq[m0 + tx * 4];
  unsigned* kb = keys + ((long)bb << 22);
  unsigned ok[4][4];
#pragma unroll
  for (int i = 0; i < 4; ++i) {
    float xxn = xxq[n0 + ty * 4 + i];
    ok[i][0] = ordkey((-xxn - (-2.f * acc[i][0])) - xxm.x);
    ok[i][1] = ordkey((-xxn - (-2.f * acc[i][1])) - xxm.y);
    ok[i][2] = ordkey((-xxn - (-2.f * acc[i][2])) - xxm.z);
    ok[i][3] = ordkey((-xxn - (-2.f * acc[i][3])) - xxm.w);
    uint4 o = make_uint4(ok[i][0], ok[i][1], ok[i][2], ok[i][3]);
    *(uint4*)&kb[(long)(n0 + ty * 4 + i) * NPTS + m0 + tx * 4] = o;
  }
  if (ti != tj) {
#pragma unroll
    for (int i = 0; i < 4; ++i)
#pragma unroll
      for (int j = 0; j < 4; ++j) Ts[(tx * 4 + j) * 68 + ty * 4 + i] = ok[i][j];
    __syncthreads();
#pragma unroll
    for (int i = 0; i < 4; ++i)
      *(uint4*)&kb[(long)(m0 + ty * 4 + i) * NPTS + n0 + tx * 4] =
          *(const uint4*)&Ts[(ty * 4 + i) * 68 + tx * 4];
  }
}

// ---- yzt body: point-major GEMM, yt[b][m][o], zt[b][m][o] ----
template <int C>
static __device__ __forceinline__ void yzt_body(char* smem, const float* __restrict__ x,
                                                long bstride, const float* __restrict__ W, int O,
                                                float* __restrict__ yt, float* __restrict__ zt,
                                                int b, int m0, int o0) {
  constexpr int KT = (C < 16) ? C : 16;
  float* Xs = (float*)smem;        // [KT][64]
  float* Wy = Xs + KT * 64;        // [KT][64]
  float* Wp = Wy + KT * 64;        // [KT][64]
  int tid = threadIdx.x, tx = tid & 15, ty = tid >> 4;
  const float* xb = x + (long)b * bstride;
  const int twoC = 2 * C;
  float accy[4][4] = {}, accp[4][4] = {};
  for (int k0 = 0; k0 < C; k0 += KT) {
    for (int lin = tid; lin < KT * 64; lin += 256) {
      int r = lin >> 6, col = lin & 63;
      Xs[r * 64 + col] = xb[(long)(k0 + r) * NPTS + m0 + col];
      float wy = W[(o0 + col) * twoC + k0 + r];
      Wy[r * 64 + col] = wy;
      Wp[r * 64 + col] = W[(o0 + col) * twoC + C + k0 + r] - wy;
    }
    __syncthreads();
#pragma unroll
    for (int kc = 0; kc < KT; ++kc) {
      float4 wv = *(const float4*)&Wy[kc * 64 + tx * 4];
      float4 pv = *(const float4*)&Wp[kc * 64 + tx * 4];
      float xm[4];
      xm[0] = Xs[kc * 64 + ty * 4 + 0]; xm[1] = Xs[kc * 64 + ty * 4 + 1];
      xm[2] = Xs[kc * 64 + ty * 4 + 2]; xm[3] = Xs[kc * 64 + ty * 4 + 3];
#pragma unroll
      for (int i = 0; i < 4; ++i) {
        accy[i][0] = fmaf(xm[i], wv.x, accy[i][0]);
        accy[i][1] = fmaf(xm[i], wv.y, accy[i][1]);
        accy[i][2] = fmaf(xm[i], wv.z, accy[i][2]);
        accy[i][3] = fmaf(xm[i], wv.w, accy[i][3]);
        accp[i][0] = fmaf(xm[i], pv.x, accp[i][0]);
        accp[i][1] = fmaf(xm[i], pv.y, accp[i][1]);
        accp[i][2] = fmaf(xm[i], pv.z, accp[i][2]);
        accp[i][3] = fmaf(xm[i], pv.w, accp[i][3]);
      }
    }
    __syncthreads();
  }
#pragma unroll
  for (int i = 0; i < 4; ++i) {
    long base = ((long)b * NPTS + m0 + ty * 4 + i) * O + o0 + tx * 4;
    *(float4*)&yt[base] = make_float4(accy[i][0], accy[i][1], accy[i][2], accy[i][3]);
    *(float4*)&zt[base] = make_float4(accp[i][0], accp[i][1], accp[i][2], accp[i][3]);
  }
}

// fused pd || yzt: blocks [0, NTRI*NB) pd; rest yzt
template <int C, int O64>
__global__ __launch_bounds__(256) void pdyzt_kernel(const float* __restrict__ x, long bstride,
                                                    const float* __restrict__ xx,
                                                    unsigned* __restrict__ keys,
                                                    const float* __restrict__ W,
                                                    float* __restrict__ yt,
                                                    float* __restrict__ zt, int npd) {
  constexpr int KT = (C < 16) ? C : 16;
  constexpr size_t S1 = (size_t)KT * 64 * 2 * 4 + 64 * 68 * 4;
  constexpr size_t S2 = (size_t)KT * 64 * 3 * 4;
  constexpr size_t SM = S1 > S2 ? S1 : S2;
  __shared__ __align__(16) char smem[SM];
  int bid = blockIdx.x;
  if (bid < npd) {
    int bb = bid % NB, t = bid / NB;
    pd_body<C>(smem, x, bstride, xx, keys, t, bb);
  } else {
    int rem = bid - npd;                // o64 * (32*NB) + my*NB + b
    int b = rem % NB; rem /= NB;
    int m0 = (rem % 32) * 64; rem /= 32;
    int o0 = rem * 64;
    yzt_body<C>(smem, x, bstride, W, O64 * 64, yt, zt, b, m0, o0);
  }
}

// ---- select: top-32 SET select (per-lane top-4 + ballot radix + verify), standalone ----
__global__ __launch_bounds__(256) void select_kernel(const unsigned* __restrict__ keys,
                                                     int* __restrict__ idxout) {
  int wave = threadIdx.x >> 6, lane = threadIdx.x & 63;
  int q = blockIdx.x * 4 + wave;
  int bloc = q >> 11, n = q & 2047;
  const uint4* rp = (const uint4*)(keys + ((long)((bloc << 11) | n) << 11));
  unsigned K[32];
#pragma unroll
  for (int t = 0; t < 8; ++t) {
    uint4 kk = rp[t * 64 + lane];
    K[4 * t + 0] = kk.x; K[4 * t + 1] = kk.y; K[4 * t + 2] = kk.z; K[4 * t + 3] = kk.w;
  }
  unsigned t0 = 0, t1 = 0, t2 = 0, t3 = 0;
#pragma unroll
  for (int s = 0; s < 32; ++s) {
    unsigned k = K[s];
    if (k > t3) {
      if (k > t1) {
        if (k > t0) { t3 = t2; t2 = t1; t1 = t0; t0 = k; }
        else        { t3 = t2; t2 = t1; t1 = k; }
      } else {
        if (k > t2) { t3 = t2; t2 = k; }
        else        { t3 = k; }
      }
    }
  }
  unsigned orv = t0 | t1 | t2 | t3, andv = t0 & t1 & t2 & t3;
#pragma unroll
  for (int xm = 32; xm >= 1; xm >>= 1) {
    orv  |= __shfl_xor(orv, xm);
    andv &= __shfl_xor(andv, xm);
  }
  unsigned V = orv ^ andv;
  unsigned P = andv & ~V;
  int need = KNN;
  for (int b = 31; b >= 0; --b) {
    unsigned bit = 1u << b;
    if (!(V & bit)) continue;
    unsigned hm = 0xFFFFFFFFu << b;
    unsigned Pb = (P & hm) | bit;
    int c = (int)__popcll(__ballot((t0 & hm) == Pb)) +
            (int)__popcll(__ballot((t1 & hm) == Pb)) +
            (int)__popcll(__ballot((t2 & hm) == Pb)) +
            (int)__popcll(__ballot((t3 & hm) == Pb));
    if (c >= need) P |= bit;
    else need -= c;
  }
  int cg = 0;
#pragma unroll
  for (int s = 0; s < 32; ++s) cg += (int)__popcll(__ballot(K[s] > P));
  if (cg > KNN - 1) {
    unsigned orf = K[0], anf = K[0];
#pragma unroll
    for (int s = 1; s < 32; ++s) { orf |= K[s]; anf &= K[s]; }
#pragma unroll
    for (int xm = 32; xm >= 1; xm >>= 1) {
      orf |= __shfl_xor(orf, xm);
      anf &= __shfl_xor(anf, xm);
    }
    unsigned Vf = orf ^ anf;
    P = anf & ~Vf;
    need = KNN;
    for (int b = 31; b >= 0; --b) {
      unsigned bit = 1u << b;
      if (!(Vf & bit)) continue;
      unsigned hm = 0xFFFFFFFFu << b;
      unsigned Pb = (P & hm) | bit;
      int c = 0;
#pragma unroll
      for (int s = 0; s < 32; ++s) c += (int)__popcll(__ballot((K[s] & hm) == Pb));
      if (c >= need) P |= bit;
      else need -= c;
    }
  }
  int* orow = idxout + ((bloc << 11) | n) * KNN;
  int base = 0;
  unsigned eqmask = 0;
#pragma unroll
  for (int s = 0; s < 32; ++s) {
    bool take = K[s] > P;
    unsigned long long bal = __ballot(take);
    if (take) {
      int pos = base + (int)__popcll(bal & ((1ull << lane) - 1ull));
      orow[pos] = ((s >> 2) << 8) + lane * 4 + (s & 3);
    }
    base += (int)__popcll(bal);
    if (K[s] == P) eqmask |= (1u << s);
  }
  int rem = KNN - base;
  for (int it = 0; it < rem; ++it) {
    unsigned mym = 0xFFFFFFFFu;
    if (eqmask) {
      int s = __ffs(eqmask) - 1;
      mym = (unsigned)(((s >> 2) << 8) + lane * 4 + (s & 3));
    }
    unsigned wm = mym;
#pragma unroll
    for (int xm = 32; xm >= 1; xm >>= 1) {
      unsigned o = __shfl_xor(wm, xm);
      wm = o < wm ? o : wm;
    }
    if (mym == wm) {
      orow[base + it] = (int)wm;
      eqmask &= eqmask - 1;
    }
  }
}

// standalone fallback kernels (bpass < NB path)
template <int C>
__global__ __launch_bounds__(256) void pdgemmsym_kernel(const float* __restrict__ x, long bstride,
                                                        const float* __restrict__ xx,
                                                        unsigned* __restrict__ keys) {
  constexpr int KT = (C < 16) ? C : 16;
  constexpr size_t SM = (size_t)KT * 64 * 2 * 4 + 64 * 68 * 4;
  __shared__ __align__(16) char smem[SM];
  pd_body<C>(smem, x, bstride, xx, keys, blockIdx.x, blockIdx.y);
}

template <int C>
__global__ __launch_bounds__(256) void yzt_kernel(const float* __restrict__ x, long bstride,
                                                  const float* __restrict__ W, int O,
                                                  float* __restrict__ yt, float* __restrict__ zt) {
  constexpr int KT = (C < 16) ? C : 16;
  constexpr size_t SM = (size_t)KT * 64 * 3 * 4;
  __shared__ __align__(16) char smem[SM];
  yzt_body<C>(smem, x, bstride, W, O, yt, zt, blockIdx.z, blockIdx.y * 64, blockIdx.x * 64);
}

// gmaxt: one wave per query n; emits xx for next layer + bf16 point-major cat copy
template <int RO>
__global__ __launch_bounds__(256) void gmaxt_kernel(const float* __restrict__ yt,
                                                    const float* __restrict__ zt,
                                                    const int* __restrict__ idx,
                                                    const float* __restrict__ g,
                                                    const float* __restrict__ bb,
                                                    float* __restrict__ out, long obstride,
                                                    float* __restrict__ xxout,
                                                    __hip_bfloat16* __restrict__ catbf, int loff) {
  constexpr int O = RO * 64;
  int wave = threadIdx.x >> 6, lane = threadIdx.x & 63;
  int n = blockIdx.x * 4 + wave, b = blockIdx.y;
  int jreg = idx[((b << 11) + n) * KNN + (lane & 31)];
  int obase = lane * RO;
  float gs[RO], bs[RO], zr[RO], acc[RO];
  loadv(zt + ((long)(b << 11) + n) * O + obase, zr);
#pragma unroll
  for (int r = 0; r < RO; ++r) {
    gs[r] = g[obase + r] * ISQ;
    bs[r] = bb[obase + r];
    acc[r] = -INFINITY;
  }
  const float* yb = yt + ((long)(b << 11)) * O + obase;
#pragma unroll
  for (int k = 0; k < KNN; ++k) {
    int j = __shfl(jreg, k);
    float yv[RO];
    loadv(yb + (long)j * O, yv);
#pragma unroll
    for (int r = 0; r < RO; ++r) {
      float v = fmaf(gs[r], yv[r] + zr[r], bs[r]);
      v = v >= 0.f ? v : 0.2f * v;
      acc[r] = fmaxf(acc[r], v);
    }
  }
  float* op = out + (long)b * obstride + (long)obase * NPTS + n;
#pragma unroll
  for (int r = 0; r < RO; ++r) op[(long)r * NPTS] = acc[r];
  __hip_bfloat16* cb = catbf + ((long)(b << 11) + n) * 512 + loff + obase;
#pragma unroll
  for (int r = 0; r < RO; ++r) cb[r] = __float2bfloat16(acc[r]);
  if (xxout) {
    float ss = 0.f;
#pragma unroll
    for (int r = 0; r < RO; ++r) ss = fmaf(acc[r], acc[r], ss);
    ss = wave_red_sum(ss);
    if (lane == 0) xxout[(b << 11) + n] = ss;
  }
}

// MFMA W5 GEMM + BN + leaky + 64n partial max. LDS-staged B, double-buffered.
__global__ __launch_bounds__(256) void gemm5m_kernel(const __hip_bfloat16* __restrict__ catbf,
                                                     const __hip_bfloat16* __restrict__ w5bf,
                                                     const float* __restrict__ g5,
                                                     const float* __restrict__ b5,
                                                     float* __restrict__ pmax) {
  __shared__ __align__(16) short Bs[2][8 * 64 * 8];
  int b = blockIdx.z, po0 = blockIdx.y * 128, n0 = blockIdx.x * 64;
  int wave = threadIdx.x >> 6, lane = threadIdx.x & 63;
  int quad = lane >> 4, l15 = lane & 15;
  const short* cbase = (const short*)catbf + ((long)(b << 11) + n0) * 512;
  const short* abase0 = (const short*)w5bf + (long)(po0 + wave * 32 + l15) * 512 + quad * 8;
  const short* abase1 = abase0 + 16 * 512;
  const short* bsrc0 = cbase + (long)lane * 512 + (2 * wave + 0) * 8;
  const short* bsrc1 = cbase + (long)lane * 512 + (2 * wave + 1) * 8;
  short* bdst0 = &Bs[0][((2 * wave + 0) * 64 + lane) * 8];
  short* bdst1 = &Bs[0][((2 * wave + 1) * 64 + lane) * 8];
  const int bufstride = 8 * 64 * 8;

  short8v Br[2][2], Ar[2][2][2];
  f32x4 acc[2][4] = {};

  Br[0][0] = *(const short8v*)(bsrc0);
  Br[0][1] = *(const short8v*)(bsrc1);
#pragma unroll
  for (int h = 0; h < 2; ++h)
#pragma unroll
    for (int j = 0; j < 2; ++j)
      Ar[0][h][j] = *(const short8v*)((h ? abase1 : abase0) + j * 32);
  *(short8v*)bdst0 = Br[0][0];
  *(short8v*)bdst1 = Br[0][1];
  Br[1][0] = *(const short8v*)(bsrc0 + 64);
  Br[1][1] = *(const short8v*)(bsrc1 + 64);
#pragma unroll
  for (int h = 0; h < 2; ++h)
#pragma unroll
    for (int j = 0; j < 2; ++j)
      Ar[1][h][j] = *(const short8v*)((h ? abase1 : abase0) + 64 + j * 32);
  __syncthreads();

  for (int it = 0; it < 8; ++it) {
    int cur = it & 1;
    const short* lb = &Bs[cur][0];
#pragma unroll
    for (int j = 0; j < 2; ++j) {
#pragma unroll
      for (int nt = 0; nt < 4; ++nt) {
        short8v bf = *(const short8v*)(lb + ((j * 4 + quad) * 64 + nt * 16 + l15) * 8);
        acc[0][nt] = __builtin_amdgcn_mfma_f32_16x16x32_bf16(Ar[cur][0][j], bf, acc[0][nt], 0, 0, 0);
        acc[1][nt] = __builtin_amdgcn_mfma_f32_16x16x32_bf16(Ar[cur][1][j], bf, acc[1][nt], 0, 0, 0);
      }
    }
    if (it < 7) {
      if (it < 6) {
        int ks = (it + 2) * 64;
        Br[cur][0] = *(const short8v*)(bsrc0 + ks);
        Br[cur][1] = *(const short8v*)(bsrc1 + ks);
#pragma unroll
        for (int h = 0; h < 2; ++h)
#pragma unroll
          for (int j = 0; j < 2; ++j)
            Ar[cur][h][j] = *(const short8v*)((h ? abase1 : abase0) + ks + j * 32);
      }
      int nb = cur ^ 1;
      *(short8v*)(bdst0 + nb * bufstride) = Br[nb][0];
      *(short8v*)(bdst1 + nb * bufstride) = Br[nb][1];
      __syncthreads();
    }
  }

#pragma unroll
  for (int h = 0; h < 2; ++h) {
#pragma unroll
    for (int r = 0; r < 4; ++r) {
      int po = po0 + wave * 32 + h * 16 + quad * 4 + r;
      float sc = g5[po] * ISQ;
      float bi = b5[po];
      float mx = -INFINITY;
#pragma unroll
      for (int nt = 0; nt < 4; ++nt) {
        float v = fmaf(sc, acc[h][nt][r], bi);
        v = v >= 0.f ? v : 0.2f * v;
        mx = fmaxf(mx, v);
      }
#pragma unroll
      for (int xm = 1; xm < 16; xm <<= 1) mx = fmaxf(mx, __shfl_xor(mx, xm));
      if (l15 == 0) pmax[(long)(b * 1024 + po) * 32 + blockIdx.x] = mx;
    }
  }
}

// merged: blocks 0..15 -> global-max reduce of pmax into v; blocks 16..17 -> lf/nf
__global__ __launch_bounds__(256) void redlfnf_kernel(const float* __restrict__ pmax,
                                                      const float* __restrict__ l,
                                                      const float* __restrict__ nn,
                                                      const float* __restrict__ W6,
                                                      const float* __restrict__ g6,
                                                      const float* __restrict__ b6,
                                                      const float* __restrict__ W7,
                                                      const float* __restrict__ g7,
                                                      const float* __restrict__ b7,
                                                      float* __restrict__ v) {
  if (blockIdx.x < 16) {
    int t = blockIdx.x * 256 + threadIdx.x;   // b*1024 + po  (4096)
    float mx = -INFINITY;
#pragma unroll
    for (int j = 0; j < 32; ++j) mx = fmaxf(mx, pmax[(long)t * 32 + j]);
    int b = t >> 10, po = t & 1023;
    v[b * 1152 + po] = mx;
  } else {
    int idx = (blockIdx.x - 16) * 256 + threadIdx.x;  // 512 work items
    int b = idx >> 7, t = idx & 127;
    if (t < 64) {
      float s = 0.f;
#pragma unroll
      for (int c = 0; c < 5; ++c) s = fmaf(W6[t * 5 + c], l[b * 5 + c], s);
      float val = fmaf(g6[t] * ISQ, s, b6[t]);
      v[b * 1152 + 1024 + t] = val >= 0.f ? val : 0.2f * val;
    } else {
      int o = t - 64;
      float s = 0.f;
#pragma unroll
      for (int c = 0; c < 7; ++c) s = fmaf(W7[o * 7 + c], nn[b * 7 + c], s);
      float val = fmaf(g7[o] * ISQ, s, b7[o]);
      v[b * 1152 + 1088 + o] = val >= 0.f ? val : 0.2f * val;
    }
  }
}

// one wave per output row; lane-strided dot + shuffle reduce
__global__ __launch_bounds__(256) void head1_kernel(const float* __restrict__ v,
                                                    const float* __restrict__ L1,
                                                    const float* __restrict__ g8,
                                                    const float* __restrict__ b8,
                                                    float* __restrict__ v1) {
  int wave = threadIdx.x >> 6, lane = threadIdx.x & 63;
  int t = blockIdx.x * 4 + wave;   // b*512 + o  (2048)
  int b = t >> 9, o = t & 511;
  const float* vb = v + b * 1152;
  const float* wr = L1 + (long)o * 1152;
  float s = 0.f;
#pragma unroll
  for (int c = lane; c < 1152; c += 64) s = fmaf(wr[c], vb[c], s);
  s = wave_red_sum(s);
  if (lane == 0) {
    float val = fmaf(g8[o] * ISQ, s, b8[o]);
    v1[t] = fmaxf(val, 0.f);
  }
}

__global__ __launch_bounds__(256) void head2_kernel(const float* __restrict__ v1,
                                                    const float* __restrict__ L2,
                                                    const float* __restrict__ L2b,
                                                    const float* __restrict__ g9,
                                                    const float* __restrict__ b9,
                                                    float* __restrict__ v2) {
  int wave = threadIdx.x >> 6, lane = threadIdx.x & 63;
  int t = blockIdx.x * 4 + wave;   // b*256 + o  (1024)
  int b = t >> 8, o = t & 255;
  const float* vb = v1 + b * 512;
  const float* wr = L2 + (long)o * 512;
  float s = 0.f;
#pragma unroll
  for (int c = lane; c < 512; c += 64) s = fmaf(wr[c], vb[c], s);
  s = wave_red_sum(s);
  if (lane == 0) {
    float sv = s + L2b[o];
    float val = fmaf(g9[o] * ISQ, sv, b9[o]);
    v2[t] = fmaxf(val, 0.f);
  }
}

__global__ __launch_bounds__(256) void head3_kernel(const float* __restrict__ v2,
                                                    const float* __restrict__ L3,
                                                    const float* __restrict__ L3b,
                                                    void* __restrict__ out,
                                                    const int* __restrict__ flag) {
  int wave = threadIdx.x >> 6, lane = threadIdx.x & 63;
  int t = blockIdx.x * 4 + wave;   // b*28 + o  (112)
  if (t >= 112) return;
  int b = t / 28, o = t % 28;
  const float* vb = v2 + b * 256;
  const float* wr = L3 + o * 256;
  float s = 0.f;
#pragma unroll
  for (int c = lane; c < 256; c += 64) s = fmaf(wr[c], vb[c], s);
  s = wave_red_sum(s);
  if (lane == 0) {
    float sv = s + L3b[o];
    if (flag[0]) ((__hip_bfloat16*)out)[t] = __float2bfloat16(sv);
    else         ((float*)out)[t] = sv;
  }
}

extern "C" void kernel_launch(void* const* d_in, const int* in_sizes, int n_in,
                              void* d_out, int out_size, void* d_ws, size_t ws_size,
                              hipStream_t stream) {
  CvtArgs ca;
  int off[NIN + 1];
  off[0] = 0;
  for (int i = 0; i < NIN; ++i) {
    ca.src[i] = d_in[i];
    off[i + 1] = off[i] + in_sizes[i];
    ca.off[i] = off[i];
  }
  ca.off[NIN] = off[NIN];
  const int total = off[NIN];

  int* flag = (int*)d_ws;
  float* fin = (float*)((char*)d_ws + 64);
  const float* xf  = fin + off[0];
  const float* lf  = fin + off[1];
  const float* nf  = fin + off[2];
  const float* W1f = fin + off[3];  const float* g1f = fin + off[4];  const float* b1f = fin + off[5];
  const float* W2f = fin + off[6];  const float* g2f = fin + off[7];  const float* b2f_ = fin + off[8];
  const float* W3f = fin + off[9];  const float* g3f = fin + off[10]; const float* b3f = fin + off[11];
  const float* W4f = fin + off[12]; const float* g4f = fin + off[13]; const float* b4f = fin + off[14];
  const float* g5f = fin + off[16]; const float* b5f = fin + off[17];
  const float* W6f = fin + off[18]; const float* g6f = fin + off[19]; const float* b6f = fin + off[20];
  const float* W7f = fin + off[21]; const float* g7f = fin + off[22]; const float* b7f = fin + off[23];
  const float* L1f = fin + off[24]; const float* g8f = fin + off[25]; const float* b8f = fin + off[26];
  const float* L2f = fin + off[27]; const float* L2bf = fin + off[28];
  const float* g9f = fin + off[29]; const float* b9f = fin + off[30];
  const float* L3f = fin + off[31]; const float* L3bf = fin + off[32];

  float* p = fin + ((total + 15) & ~15);
  float* cat  = p;                               // 4*512*2048 (fp32, channel-major)
  float* yb   = cat + 4 * 512 * NPTS;            // 4*2048*256 (point-major)
  float* zb   = yb + 4 * 256 * NPTS;             // 4*2048*256 (point-major)
  float* xxb  = zb + 4 * 256 * NPTS;             // 4*2048
  int*   idxb = (int*)(xxb + 4 * NPTS);          // 4*2048*32
  float* pmax = (float*)(idxb + 4 * NPTS * KNN); // 4*1024*32
  float* vb   = pmax + 4 * 1024 * 32;            // 4*1152
  float* v1b  = vb + 4 * 1152;                   // 4*512
  float* v2b  = v1b + 4 * 512;                   // 4*256
  __hip_bfloat16* w5bf  = (__hip_bfloat16*)(v2b + 4 * 256);           // 1024*512 bf16
  __hip_bfloat16* catbf = w5bf + 1024 * 512;                          // 4*2048*512 bf16
  unsigned* keys_tail = (unsigned*)(catbf + (size_t)4 * NPTS * 512);

  size_t need_full = (size_t)((char*)(keys_tail + (size_t)NB * NPTS * NPTS) - (char*)d_ws);
  int bpass = (ws_size >= need_full) ? NB : 1;
  unsigned* keys = (bpass == NB) ? keys_tail : (unsigned*)yb;

  const long bst1 = 3L * NPTS;
  const long bstc = 512L * NPTS;
  const int NTRI = 32 * 33 / 2;   // 528 triangular 64x64 tiles
  const int NPD = NTRI * NB;      // 2112 pd blocks in fused kernel
  const int nb1 = (total + 255) / 256;

  detect_kernel<<<1, 64, 0, stream>>>((const unsigned short*)d_in[0], flag);
  cvt_all_kernel<<<nb1 + 2048 + 32, 256, 0, stream>>>(ca, fin, total, nb1, w5bf, xxb, flag);

  // ---- layer 1: C=3, O=64
  if (bpass == NB) {
    pdyzt_kernel<3, 1><<<NPD + 1 * 32 * NB, 256, 0, stream>>>(xf, bst1, xxb, keys, W1f, yb, zb, NPD);
    select_kernel<<<512 * NB, 256, 0, stream>>>(keys, idxb);
  } else {
    for (int b0 = 0; b0 < NB; b0 += bpass) {
      pdgemmsym_kernel<3><<<dim3(NTRI, bpass), 256, 0, stream>>>(xf + b0 * bst1, bst1, xxb + b0 * NPTS, keys);
      select_kernel<<<512 * bpass, 256, 0, stream>>>(keys, idxb + (long)b0 * NPTS * KNN);
    }
    yzt_kernel<3><<<dim3(1, 32, NB), 256, 0, stream>>>(xf, bst1, W1f, 64, yb, zb);
  }
  gmaxt_kernel<1><<<dim3(512, NB), 256, 0, stream>>>(yb, zb, idxb, g1f, b1f, cat, bstc, xxb, catbf, 0);

  // ---- layer 2: C=64, O=64
  if (bpass == NB) {
    pdyzt_kernel<64, 1><<<NPD + 1 * 32 * NB, 256, 0, stream>>>(cat, bstc, xxb, keys, W2f, yb, zb, NPD);
    select_kernel<<<512 * NB, 256, 0, stream>>>(keys, idxb);
  } else {
    for (int b0 = 0; b0 < NB; b0 += bpass) {
      pdgemmsym_kernel<64><<<dim3(NTRI, bpass), 256, 0, stream>>>(cat + b0 * bstc, bstc, xxb + b0 * NPTS, keys);
      select_kernel<<<512 * bpass, 256, 0, stream>>>(keys, idxb + (long)b0 * NPTS * KNN);
    }
    yzt_kernel<64><<<dim3(1, 32, NB), 256, 0, stream>>>(cat, bstc, W2f, 64, yb, zb);
  }
  gmaxt_kernel<1><<<dim3(512, NB), 256, 0, stream>>>(yb, zb, idxb, g2f, b2f_, cat + 64L * NPTS, bstc, xxb, catbf, 64);

  // ---- layer 3: C=64, O=128
  if (bpass == NB) {
    pdyzt_kernel<64, 2><<<NPD + 2 * 32 * NB, 256, 0, stream>>>(cat + 64L * NPTS, bstc, xxb, keys, W3f, yb, zb, NPD);
    select_kernel<<<512 * NB, 256, 0, stream>>>(keys, idxb);
  } else {
    for (int b0 = 0; b0 < NB; b0 += bpass) {
      pdgemmsym_kernel<64><<<dim3(NTRI, bpass), 256, 0, stream>>>(cat + 64L * NPTS + b0 * bstc, bstc, xxb + b0 * NPTS, keys);
      select_kernel<<<512 * bpass, 256, 0, stream>>>(keys, idxb + (long)b0 * NPTS * KNN);
    }
    yzt_kernel<64><<<dim3(2, 32, NB), 256, 0, stream>>>(cat + 64L * NPTS, bstc, W3f, 128, yb, zb);
  }
  gmaxt_kernel<2><<<dim3(512, NB), 256, 0, stream>>>(yb, zb, idxb, g3f, b3f, cat + 128L * NPTS, bstc, xxb, catbf, 128);

  // ---- layer 4: C=128, O=256
  if (bpass == NB) {
    pdyzt_kernel<128, 4><<<NPD + 4 * 32 * NB, 256, 0, stream>>>(cat + 128L * NPTS, bstc, xxb, keys, W4f, yb, zb, NPD);
    select_kernel<<<512 * NB, 256, 0, stream>>>(keys, idxb);
  } else {
    for (int b0 = 0; b0 < NB; b0 += bpass) {
      pdgemmsym_kernel<128><<<dim3(NTRI, bpass), 256, 0, stream>>>(cat + 128L * NPTS + b0 * bstc, bstc, xxb + b0 * NPTS, keys);
      select_kernel<<<512 * bpass, 256, 0, stream>>>(keys, idxb + (long)b0 * NPTS * KNN);
    }
    yzt_kernel<128><<<dim3(4, 32, NB), 256, 0, stream>>>(cat + 128L * NPTS, bstc, W4f, 256, yb, zb);
  }
  gmaxt_kernel<4><<<dim3(512, NB), 256, 0, stream>>>(yb, zb, idxb, g4f, b4f, cat + 256L * NPTS, bstc, (float*)nullptr, catbf, 256);

  // ---- conv5 (bf16 MFMA, LDS-staged B, double-buffered) + BN + leaky + global max
  gemm5m_kernel<<<dim3(32, 8, NB), 256, 0, stream>>>(catbf, w5bf, g5f, b5f, pmax);
  redlfnf_kernel<<<18, 256, 0, stream>>>(pmax, lf, nf, W6f, g6f, b6f, W7f, g7f, b7f, vb);

  head1_kernel<<<512, 256, 0, stream>>>(vb, L1f, g8f, b8f, v1b);
  head2_kernel<<<256, 256, 0, stream>>>(v1b, L2f, L2bf, g9f, b9f, v2b);
  head3_kernel<<<28, 256, 0, stream>>>(v2b, L3f, L3bf, d_out, flag);
}

// Round 16
// 536.383 us; speedup vs baseline: 1.0167x; 1.0167x over previous
//
#include <hip/hip_runtime.h>
#include <hip/hip_bf16.h>

#define NPTS 2048
#define NB 4
#define KNN 32
#define NIN 33

static __device__ __forceinline__ float b2f(__hip_bfloat16 v) { return __bfloat162float(v); }
#define ISQ 0.99999499996875f /* 1/sqrt(1+1e-5) */

typedef __attribute__((ext_vector_type(8))) short short8v;   // 8 bf16 (4 VGPRs)
typedef __attribute__((ext_vector_type(4))) float f32x4;

// monotone order-preserving key for fp32 (no NaNs): a<b  <=>  ordkey(a)<ordkey(b)
static __device__ __forceinline__ unsigned ordkey(float f) {
  unsigned u = __float_as_uint(f);
  return u ^ (unsigned)(((int)u >> 31) | 0x80000000);
}

static __device__ __forceinline__ void loadv(const float* p, float (&d)[1]) { d[0] = *p; }
static __device__ __forceinline__ void loadv(const float* p, float (&d)[2]) {
  float2 v = *(const float2*)p; d[0] = v.x; d[1] = v.y;
}
static __device__ __forceinline__ void loadv(const float* p, float (&d)[4]) {
  float4 v = *(const float4*)p; d[0] = v.x; d[1] = v.y; d[2] = v.z; d[3] = v.w;
}

static __device__ __forceinline__ float wave_red_sum(float s) {
#pragma unroll
  for (int off = 32; off > 0; off >>= 1) s += __shfl_xor(s, off);
  return s;
}

// ---- dtype detect: flag=1 if buffer is bf16, 0 if fp32 ----
__global__ __launch_bounds__(64) void detect_kernel(const unsigned short* __restrict__ x,
                                                    int* __restrict__ flag) {
  int cnt = 0;
  for (int i = threadIdx.x; i < 512; i += 64) {
    unsigned e = (x[i] >> 7) & 0xFFu;
    if (e >= 0xC6u) cnt++;
  }
#pragma unroll
  for (int off = 32; off > 0; off >>= 1) cnt += __shfl_down(cnt, off);
  if (threadIdx.x == 0) flag[0] = (cnt == 0) ? 1 : 0;
}

struct CvtArgs {
  const void* src[NIN];
  int off[NIN + 1];
};

// blocks [0, nb1): convert all inputs into fp32 pool.
// blocks [nb1, nb1+2048): convert W5 to bf16.
// blocks [nb1+2048, +32): xx for layer 1 straight from raw input.
__global__ __launch_bounds__(256) void cvt_all_kernel(CvtArgs a, float* __restrict__ out,
                                                      int total, int nb1,
                                                      __hip_bfloat16* __restrict__ w5bf,
                                                      float* __restrict__ xxb,
                                                      const int* __restrict__ flag) {
  int fl = flag[0];
  if ((int)blockIdx.x < nb1) {
    int t = blockIdx.x * 256 + threadIdx.x;
    if (t >= total) return;
    int s = 0;
    while (t >= a.off[s + 1]) s++;
    int j = t - a.off[s];
    float v;
    if (fl) v = b2f(((const __hip_bfloat16*)a.src[s])[j]);
    else    v = ((const float*)a.src[s])[j];
    out[t] = v;
  } else if ((int)blockIdx.x < nb1 + 2048) {
    int t = (blockIdx.x - nb1) * 256 + threadIdx.x;   // 1024*512
    if (fl) w5bf[t] = ((const __hip_bfloat16*)a.src[15])[t];
    else    w5bf[t] = __float2bfloat16(((const float*)a.src[15])[t]);
  } else {
    int t = (blockIdx.x - nb1 - 2048) * 256 + threadIdx.x;  // b*NPTS + m (8192)
    int b = t >> 11, m = t & 2047;
    float s = 0.f;
#pragma unroll
    for (int c = 0; c < 3; ++c) {
      long o = ((long)b * 3 + c) * NPTS + m;
      float v = fl ? b2f(((const __hip_bfloat16*)a.src[0])[o])
                   : ((const float*)a.src[0])[o];
      s = fmaf(v, v, s);
    }
    xxb[t] = s;
  }
}

// ---- shared select machinery: top-4 prefilter + ballot radix + verify + emission ----
// MODE 0: K[s] holds m = (s>>2)*256 + lane*4 + (s&3)   (uint4 keys layout)
// MODE 1: K[s] holds m = s*64 + lane                    (knn3 in-register layout)
template <int MODE>
static __device__ __forceinline__ int midx(int s, int lane) {
  return MODE == 0 ? (((s >> 2) << 8) + lane * 4 + (s & 3)) : (s * 64 + lane);
}

template <int MODE>
static __device__ __forceinline__ void select_from_K(unsigned (&K)[32], int lane,
                                                     int* __restrict__ orow) {
  unsigned t0 = 0, t1 = 0, t2 = 0, t3 = 0;
#pragma unroll
  for (int s = 0; s < 32; ++s) {
    unsigned k = K[s];
    if (k > t3) {
      if (k > t1) {
        if (k > t0) { t3 = t2; t2 = t1; t1 = t0; t0 = k; }
        else        { t3 = t2; t2 = t1; t1 = k; }
      } else {
        if (k > t2) { t3 = t2; t2 = k; }
        else        { t3 = k; }
      }
    }
  }
  unsigned orv = t0 | t1 | t2 | t3, andv = t0 & t1 & t2 & t3;
#pragma unroll
  for (int xm = 32; xm >= 1; xm >>= 1) {
    orv  |= __shfl_xor(orv, xm);
    andv &= __shfl_xor(andv, xm);
  }
  unsigned V = orv ^ andv;
  unsigned P = andv & ~V;
  int need = KNN;
  for (int b = 31; b >= 0; --b) {
    unsigned bit = 1u << b;
    if (!(V & bit)) continue;
    unsigned hm = 0xFFFFFFFFu << b;
    unsigned Pb = (P & hm) | bit;
    int c = (int)__popcll(__ballot((t0 & hm) == Pb)) +
            (int)__popcll(__ballot((t1 & hm) == Pb)) +
            (int)__popcll(__ballot((t2 & hm) == Pb)) +
            (int)__popcll(__ballot((t3 & hm) == Pb));
    if (c >= need) P |= bit;
    else need -= c;
  }
  int cg = 0;
#pragma unroll
  for (int s = 0; s < 32; ++s) cg += (int)__popcll(__ballot(K[s] > P));
  if (cg > KNN - 1) {
    unsigned orf = K[0], anf = K[0];
#pragma unroll
    for (int s = 1; s < 32; ++s) { orf |= K[s]; anf &= K[s]; }
#pragma unroll
    for (int xm = 32; xm >= 1; xm >>= 1) {
      orf |= __shfl_xor(orf, xm);
      anf &= __shfl_xor(anf, xm);
    }
    unsigned Vf = orf ^ anf;
    P = anf & ~Vf;
    need = KNN;
    for (int b = 31; b >= 0; --b) {
      unsigned bit = 1u << b;
      if (!(Vf & bit)) continue;
      unsigned hm = 0xFFFFFFFFu << b;
      unsigned Pb = (P & hm) | bit;
      int c = 0;
#pragma unroll
      for (int s = 0; s < 32; ++s) c += (int)__popcll(__ballot((K[s] & hm) == Pb));
      if (c >= need) P |= bit;
      else need -= c;
    }
  }
  int base = 0;
  unsigned eqmask = 0;
#pragma unroll
  for (int s = 0; s < 32; ++s) {
    bool take = K[s] > P;
    unsigned long long bal = __ballot(take);
    if (take) {
      int pos = base + (int)__popcll(bal & ((1ull << lane) - 1ull));
      orow[pos] = midx<MODE>(s, lane);
    }
    base += (int)__popcll(bal);
    if (K[s] == P) eqmask |= (1u << s);
  }
  int rem = KNN - base;
  for (int it = 0; it < rem; ++it) {
    unsigned mym = 0xFFFFFFFFu;
    if (eqmask) {
      int s = __ffs(eqmask) - 1;        // per-lane smallest m (m increases with s)
      mym = (unsigned)midx<MODE>(s, lane);
    }
    unsigned wm = mym;
#pragma unroll
    for (int xm = 32; xm >= 1; xm >>= 1) {
      unsigned o = __shfl_xor(wm, xm);
      wm = o < wm ? o : wm;
    }
    if (mym == wm) {
      orow[base + it] = (int)wm;
      eqmask &= eqmask - 1;
    }
  }
}

// ---- knn3: fused pd+select for layer 1 (C=3), no keys buffer.
// One block = 4 waves = 4 queries; x[3][2048]+xx staged in LDS (32 KB).
// pd computed with the SAME fmaf order as pd_body/cvt-xx -> bit-identical keys.
__global__ __launch_bounds__(256) void knn3_kernel(const float* __restrict__ xf,
                                                   const float* __restrict__ xxb,
                                                   int* __restrict__ idxout) {
  __shared__ float xs[3 * NPTS];
  __shared__ float xxs[NPTS];
  int b = blockIdx.y;
  int tid = threadIdx.x, wave = tid >> 6, lane = tid & 63;
  const float* xb = xf + (long)b * 3 * NPTS;
  for (int i = tid; i < 3 * NPTS; i += 256) xs[i] = xb[i];
  for (int i = tid; i < NPTS; i += 256) xxs[i] = xxb[(b << 11) + i];
  __syncthreads();
  int n = blockIdx.x * 4 + wave;
  float q0 = xs[n], q1 = xs[NPTS + n], q2 = xs[2 * NPTS + n];
  float xxn = xxs[n];
  unsigned K[32];
#pragma unroll
  for (int s = 0; s < 32; ++s) {
    int m = s * 64 + lane;
    float d = 0.f;
    d = fmaf(q0, xs[m], d);
    d = fmaf(q1, xs[NPTS + m], d);
    d = fmaf(q2, xs[2 * NPTS + m], d);
    float pdv = (-xxn - (-2.f * d)) - xxs[m];
    K[s] = ordkey(pdv);
  }
  select_from_K<1>(K, lane, idxout + (((b << 11) | n) * KNN));
}

// ---- pd body: 64x64 symmetric tile (triangular id), LDS Ts mirror ----
template <int C>
static __device__ __forceinline__ void pd_body(char* smem, const float* __restrict__ x,
                                               long bstride, const float* __restrict__ xx,
                                               unsigned* __restrict__ keys, int t, int bb) {
  constexpr int KT = (C < 16) ? C : 16;
  float* At = (float*)smem;                  // [KT][64]
  float* Bt = At + KT * 64;                  // [KT][64]
  unsigned* Ts = (unsigned*)(Bt + KT * 64);  // [64][68]
  int tj = (int)((sqrtf(8.f * (float)t + 1.f) - 1.f) * 0.5f);
  while ((tj + 1) * (tj + 2) / 2 <= t) tj++;
  while (tj * (tj + 1) / 2 > t) tj--;
  int ti = t - tj * (tj + 1) / 2;            // ti <= tj
  int n0 = ti * 64, m0 = tj * 64;
  int tid = threadIdx.x, tx = tid & 15, ty = tid >> 4;
  const float* xb = x + (long)bb * bstride;
  float acc[4][4] = {};
  for (int k0 = 0; k0 < C; k0 += KT) {
    for (int lin = tid; lin < KT * 64; lin += 256) {
      int r = lin >> 6, col = lin & 63;
      At[r * 64 + col] = xb[(long)(k0 + r) * NPTS + n0 + col];
      Bt[r * 64 + col] = xb[(long)(k0 + r) * NPTS + m0 + col];
    }
    __syncthreads();
#pragma unroll
    for (int kc = 0; kc < KT; ++kc) {
      float4 av = *(const float4*)&At[kc * 64 + ty * 4];
      float4 bv = *(const float4*)&Bt[kc * 64 + tx * 4];
      acc[0][0] = fmaf(av.x, bv.x, acc[0][0]); acc[0][1] = fmaf(av.x, bv.y, acc[0][1]);
      acc[0][2] = fmaf(av.x, bv.z, acc[0][2]); acc[0][3] = fmaf(av.x, bv.w, acc[0][3]);
      acc[1][0] = fmaf(av.y, bv.x, acc[1][0]); acc[1][1] = fmaf(av.y, bv.y, acc[1][1]);
      acc[1][2] = fmaf(av.y, bv.z, acc[1][2]); acc[1][3] = fmaf(av.y, bv.w, acc[1][3]);
      acc[2][0] = fmaf(av.z, bv.x, acc[2][0]); acc[2][1] = fmaf(av.z, bv.y, acc[2][1]);
      acc[2][2] = fmaf(av.z, bv.z, acc[2][2]); acc[2][3] = fmaf(av.z, bv.w, acc[2][3]);
      acc[3][0] = fmaf(av.w, bv.x, acc[3][0]); acc[3][1] = fmaf(av.w, bv.y, acc[3][1]);
      acc[3][2] = fmaf(av.w, bv.z, acc[3][2]); acc[3][3] = fmaf(av.w, bv.w, acc[3][3]);
    }
    __syncthreads();
  }
  const float* xxq = xx + (long)bb * NPTS;
  float4 xxm = *(const float4*)&xxq[m0 + tx * 4];
  unsigned* kb = keys + ((long)bb << 22);
  unsigned ok[4][4];
#pragma unroll
  for (int i = 0; i < 4; ++i) {
    float xxn = xxq[n0 + ty * 4 + i];
    ok[i][0] = ordkey((-xxn - (-2.f * acc[i][0])) - xxm.x);
    ok[i][1] = ordkey((-xxn - (-2.f * acc[i][1])) - xxm.y);
    ok[i][2] = ordkey((-xxn - (-2.f * acc[i][2])) - xxm.z);
    ok[i][3] = ordkey((-xxn - (-2.f * acc[i][3])) - xxm.w);
    uint4 o = make_uint4(ok[i][0], ok[i][1], ok[i][2], ok[i][3]);
    *(uint4*)&kb[(long)(n0 + ty * 4 + i) * NPTS + m0 + tx * 4] = o;
  }
  if (ti != tj) {
#pragma unroll
    for (int i = 0; i < 4; ++i)
#pragma unroll
      for (int j = 0; j < 4; ++j) Ts[(tx * 4 + j) * 68 + ty * 4 + i] = ok[i][j];
    __syncthreads();
#pragma unroll
    for (int i = 0; i < 4; ++i)
      *(uint4*)&kb[(long)(m0 + ty * 4 + i) * NPTS + n0 + tx * 4] =
          *(const uint4*)&Ts[(ty * 4 + i) * 68 + tx * 4];
  }
}

// ---- yzt body: point-major GEMM, yt[b][m][o], zt[b][m][o] ----
template <int C>
static __device__ __forceinline__ void yzt_body(char* smem, const float* __restrict__ x,
                                                long bstride, const float* __restrict__ W, int O,
                                                float* __restrict__ yt, float* __restrict__ zt,
                                                int b, int m0, int o0) {
  constexpr int KT = (C < 16) ? C : 16;
  float* Xs = (float*)smem;        // [KT][64]
  float* Wy = Xs + KT * 64;        // [KT][64]
  float* Wp = Wy + KT * 64;        // [KT][64]
  int tid = threadIdx.x, tx = tid & 15, ty = tid >> 4;
  const float* xb = x + (long)b * bstride;
  const int twoC = 2 * C;
  float accy[4][4] = {}, accp[4][4] = {};
  for (int k0 = 0; k0 < C; k0 += KT) {
    for (int lin = tid; lin < KT * 64; lin += 256) {
      int r = lin >> 6, col = lin & 63;
      Xs[r * 64 + col] = xb[(long)(k0 + r) * NPTS + m0 + col];
      float wy = W[(o0 + col) * twoC + k0 + r];
      Wy[r * 64 + col] = wy;
      Wp[r * 64 + col] = W[(o0 + col) * twoC + C + k0 + r] - wy;
    }
    __syncthreads();
#pragma unroll
    for (int kc = 0; kc < KT; ++kc) {
      float4 wv = *(const float4*)&Wy[kc * 64 + tx * 4];
      float4 pv = *(const float4*)&Wp[kc * 64 + tx * 4];
      float xm[4];
      xm[0] = Xs[kc * 64 + ty * 4 + 0]; xm[1] = Xs[kc * 64 + ty * 4 + 1];
      xm[2] = Xs[kc * 64 + ty * 4 + 2]; xm[3] = Xs[kc * 64 + ty * 4 + 3];
#pragma unroll
      for (int i = 0; i < 4; ++i) {
        accy[i][0] = fmaf(xm[i], wv.x, accy[i][0]);
        accy[i][1] = fmaf(xm[i], wv.y, accy[i][1]);
        accy[i][2] = fmaf(xm[i], wv.z, accy[i][2]);
        accy[i][3] = fmaf(xm[i], wv.w, accy[i][3]);
        accp[i][0] = fmaf(xm[i], pv.x, accp[i][0]);
        accp[i][1] = fmaf(xm[i], pv.y, accp[i][1]);
        accp[i][2] = fmaf(xm[i], pv.z, accp[i][2]);
        accp[i][3] = fmaf(xm[i], pv.w, accp[i][3]);
      }
    }
    __syncthreads();
  }
#pragma unroll
  for (int i = 0; i < 4; ++i) {
    long base = ((long)b * NPTS + m0 + ty * 4 + i) * O + o0 + tx * 4;
    *(float4*)&yt[base] = make_float4(accy[i][0], accy[i][1], accy[i][2], accy[i][3]);
    *(float4*)&zt[base] = make_float4(accp[i][0], accp[i][1], accp[i][2], accp[i][3]);
  }
}

// ---- select body (keys layout) ----
static __device__ __forceinline__ void select_body(const unsigned* __restrict__ keys,
                                                   int* __restrict__ idxout, int q) {
  int lane = threadIdx.x & 63;
  int bloc = q >> 11, n = q & 2047;
  const uint4* rp = (const uint4*)(keys + ((long)((bloc << 11) | n) << 11));
  unsigned K[32];
#pragma unroll
  for (int t = 0; t < 8; ++t) {
    uint4 kk = rp[t * 64 + lane];
    K[4 * t + 0] = kk.x; K[4 * t + 1] = kk.y; K[4 * t + 2] = kk.z; K[4 * t + 3] = kk.w;
  }
  select_from_K<0>(K, lane, idxout + ((bloc << 11) | n) * KNN);
}

// fused: blocks [0,nsel) -> select; blocks [nsel, ...) -> yzt (r14 pairing: VALU + memory)
template <int C, int O64>
__global__ __launch_bounds__(256) void selyzt_kernel(const unsigned* __restrict__ keys,
                                                     int* __restrict__ idxout,
                                                     const float* __restrict__ x, long bstride,
                                                     const float* __restrict__ W,
                                                     float* __restrict__ yt,
                                                     float* __restrict__ zt, int nsel) {
  constexpr int KT = (C < 16) ? C : 16;
  __shared__ __align__(16) char smem[(size_t)KT * 64 * 3 * 4];
  if ((int)blockIdx.x < nsel) {
    int wave = threadIdx.x >> 6;
    select_body(keys, idxout, blockIdx.x * 4 + wave);
  } else {
    int rem = blockIdx.x - nsel;           // o64 * (32*NB) + my*NB + b
    int b = rem % NB; rem /= NB;
    int m0 = (rem % 32) * 64; rem /= 32;
    int o0 = rem * 64;
    yzt_body<C>(smem, x, bstride, W, O64 * 64, yt, zt, b, m0, o0);
  }
}

// standalone kernels
__global__ __launch_bounds__(256) void select_kernel(const unsigned* __restrict__ keys,
                                                     int* __restrict__ idxout) {
  int wave = threadIdx.x >> 6;
  select_body(keys, idxout, blockIdx.x * 4 + wave);
}

template <int C>
__global__ __launch_bounds__(256) void pdgemmsym_kernel(const float* __restrict__ x, long bstride,
                                                        const float* __restrict__ xx,
                                                        unsigned* __restrict__ keys) {
  constexpr int KT = (C < 16) ? C : 16;
  constexpr size_t SM = (size_t)KT * 64 * 2 * 4 + 64 * 68 * 4;
  __shared__ __align__(16) char smem[SM];
  pd_body<C>(smem, x, bstride, xx, keys, blockIdx.x, blockIdx.y);
}

template <int C>
__global__ __launch_bounds__(256) void yzt_kernel(const float* __restrict__ x, long bstride,
                                                  const float* __restrict__ W, int O,
                                                  float* __restrict__ yt, float* __restrict__ zt) {
  constexpr int KT = (C < 16) ? C : 16;
  constexpr size_t SM = (size_t)KT * 64 * 3 * 4;
  __shared__ __align__(16) char smem[SM];
  yzt_body<C>(smem, x, bstride, W, O, yt, zt, blockIdx.z, blockIdx.y * 64, blockIdx.x * 64);
}

// gmaxt: one wave per query n; emits xx for next layer + bf16 point-major cat copy
template <int RO>
__global__ __launch_bounds__(256) void gmaxt_kernel(const float* __restrict__ yt,
                                                    const float* __restrict__ zt,
                                                    const int* __restrict__ idx,
                                                    const float* __restrict__ g,
                                                    const float* __restrict__ bb,
                                                    float* __restrict__ out, long obstride,
                                                    float* __restrict__ xxout,
                                                    __hip_bfloat16* __restrict__ catbf, int loff) {
  constexpr int O = RO * 64;
  int wave = threadIdx.x >> 6, lane = threadIdx.x & 63;
  int n = blockIdx.x * 4 + wave, b = blockIdx.y;
  int jreg = idx[((b << 11) + n) * KNN + (lane & 31)];
  int obase = lane * RO;
  float gs[RO], bs[RO], zr[RO], acc[RO];
  loadv(zt + ((long)(b << 11) + n) * O + obase, zr);
#pragma unroll
  for (int r = 0; r < RO; ++r) {
    gs[r] = g[obase + r] * ISQ;
    bs[r] = bb[obase + r];
    acc[r] = -INFINITY;
  }
  const float* yb = yt + ((long)(b << 11)) * O + obase;
#pragma unroll
  for (int k = 0; k < KNN; ++k) {
    int j = __shfl(jreg, k);
    float yv[RO];
    loadv(yb + (long)j * O, yv);
#pragma unroll
    for (int r = 0; r < RO; ++r) {
      float v = fmaf(gs[r], yv[r] + zr[r], bs[r]);
      v = v >= 0.f ? v : 0.2f * v;
      acc[r] = fmaxf(acc[r], v);
    }
  }
  float* op = out + (long)b * obstride + (long)obase * NPTS + n;
#pragma unroll
  for (int r = 0; r < RO; ++r) op[(long)r * NPTS] = acc[r];
  __hip_bfloat16* cb = catbf + ((long)(b << 11) + n) * 512 + loff + obase;
#pragma unroll
  for (int r = 0; r < RO; ++r) cb[r] = __float2bfloat16(acc[r]);
  if (xxout) {
    float ss = 0.f;
#pragma unroll
    for (int r = 0; r < RO; ++r) ss = fmaf(acc[r], acc[r], ss);
    ss = wave_red_sum(ss);
    if (lane == 0) xxout[(b << 11) + n] = ss;
  }
}

// MFMA W5 GEMM + BN + leaky + 64n partial max. LDS-staged B, double-buffered.
__global__ __launch_bounds__(256) void gemm5m_kernel(const __hip_bfloat16* __restrict__ catbf,
                                                     const __hip_bfloat16* __restrict__ w5bf,
                                                     const float* __restrict__ g5,
                                                     const float* __restrict__ b5,
                                                     float* __restrict__ pmax) {
  __shared__ __align__(16) short Bs[2][8 * 64 * 8];
  int b = blockIdx.z, po0 = blockIdx.y * 128, n0 = blockIdx.x * 64;
  int wave = threadIdx.x >> 6, lane = threadIdx.x & 63;
  int quad = lane >> 4, l15 = lane & 15;
  const short* cbase = (const short*)catbf + ((long)(b << 11) + n0) * 512;
  const short* abase0 = (const short*)w5bf + (long)(po0 + wave * 32 + l15) * 512 + quad * 8;
  const short* abase1 = abase0 + 16 * 512;
  const short* bsrc0 = cbase + (long)lane * 512 + (2 * wave + 0) * 8;
  const short* bsrc1 = cbase + (long)lane * 512 + (2 * wave + 1) * 8;
  short* bdst0 = &Bs[0][((2 * wave + 0) * 64 + lane) * 8];
  short* bdst1 = &Bs[0][((2 * wave + 1) * 64 + lane) * 8];
  const int bufstride = 8 * 64 * 8;

  short8v Br[2][2], Ar[2][2][2];
  f32x4 acc[2][4] = {};

  Br[0][0] = *(const short8v*)(bsrc0);
  Br[0][1] = *(const short8v*)(bsrc1);
#pragma unroll
  for (int h = 0; h < 2; ++h)
#pragma unroll
    for (int j = 0; j < 2; ++j)
      Ar[0][h][j] = *(const short8v*)((h ? abase1 : abase0) + j * 32);
  *(short8v*)bdst0 = Br[0][0];
  *(short8v*)bdst1 = Br[0][1];
  Br[1][0] = *(const short8v*)(bsrc0 + 64);
  Br[1][1] = *(const short8v*)(bsrc1 + 64);
#pragma unroll
  for (int h = 0; h < 2; ++h)
#pragma unroll
    for (int j = 0; j < 2; ++j)
      Ar[1][h][j] = *(const short8v*)((h ? abase1 : abase0) + 64 + j * 32);
  __syncthreads();

  for (int it = 0; it < 8; ++it) {
    int cur = it & 1;
    const short* lb = &Bs[cur][0];
#pragma unroll
    for (int j = 0; j < 2; ++j) {
#pragma unroll
      for (int nt = 0; nt < 4; ++nt) {
        short8v bf = *(const short8v*)(lb + ((j * 4 + quad) * 64 + nt * 16 + l15) * 8);
        acc[0][nt] = __builtin_amdgcn_mfma_f32_16x16x32_bf16(Ar[cur][0][j], bf, acc[0][nt], 0, 0, 0);
        acc[1][nt] = __builtin_amdgcn_mfma_f32_16x16x32_bf16(Ar[cur][1][j], bf, acc[1][nt], 0, 0, 0);
      }
    }
    if (it < 7) {
      if (it < 6) {
        int ks = (it + 2) * 64;
        Br[cur][0] = *(const short8v*)(bsrc0 + ks);
        Br[cur][1] = *(const short8v*)(bsrc1 + ks);
#pragma unroll
        for (int h = 0; h < 2; ++h)
#pragma unroll
          for (int j = 0; j < 2; ++j)
            Ar[cur][h][j] = *(const short8v*)((h ? abase1 : abase0) + ks + j * 32);
      }
      int nb = cur ^ 1;
      *(short8v*)(bdst0 + nb * bufstride) = Br[nb][0];
      *(short8v*)(bdst1 + nb * bufstride) = Br[nb][1];
      __syncthreads();
    }
  }

#pragma unroll
  for (int h = 0; h < 2; ++h) {
#pragma unroll
    for (int r = 0; r < 4; ++r) {
      int po = po0 + wave * 32 + h * 16 + quad * 4 + r;
      float sc = g5[po] * ISQ;
      float bi = b5[po];
      float mx = -INFINITY;
#pragma unroll
      for (int nt = 0; nt < 4; ++nt) {
        float v = fmaf(sc, acc[h][nt][r], bi);
        v = v >= 0.f ? v : 0.2f * v;
        mx = fmaxf(mx, v);
      }
#pragma unroll
      for (int xm = 1; xm < 16; xm <<= 1) mx = fmaxf(mx, __shfl_xor(mx, xm));
      if (l15 == 0) pmax[(long)(b * 1024 + po) * 32 + blockIdx.x] = mx;
    }
  }
}

// merged: blocks 0..15 -> global-max reduce of pmax into v; blocks 16..17 -> lf/nf
__global__ __launch_bounds__(256) void redlfnf_kernel(const float* __restrict__ pmax,
                                                      const float* __restrict__ l,
                                                      const float* __restrict__ nn,
                                                      const float* __restrict__ W6,
                                                      const float* __restrict__ g6,
                                                      const float* __restrict__ b6,
                                                      const float* __restrict__ W7,
                                                      const float* __restrict__ g7,
                                                      const float* __restrict__ b7,
                                                      float* __restrict__ v) {
  if (blockIdx.x < 16) {
    int t = blockIdx.x * 256 + threadIdx.x;   // b*1024 + po  (4096)
    float mx = -INFINITY;
#pragma unroll
    for (int j = 0; j < 32; ++j) mx = fmaxf(mx, pmax[(long)t * 32 + j]);
    int b = t >> 10, po = t & 1023;
    v[b * 1152 + po] = mx;
  } else {
    int idx = (blockIdx.x - 16) * 256 + threadIdx.x;  // 512 work items
    int b = idx >> 7, t = idx & 127;
    if (t < 64) {
      float s = 0.f;
#pragma unroll
      for (int c = 0; c < 5; ++c) s = fmaf(W6[t * 5 + c], l[b * 5 + c], s);
      float val = fmaf(g6[t] * ISQ, s, b6[t]);
      v[b * 1152 + 1024 + t] = val >= 0.f ? val : 0.2f * val;
    } else {
      int o = t - 64;
      float s = 0.f;
#pragma unroll
      for (int c = 0; c < 7; ++c) s = fmaf(W7[o * 7 + c], nn[b * 7 + c], s);
      float val = fmaf(g7[o] * ISQ, s, b7[o]);
      v[b * 1152 + 1088 + o] = val >= 0.f ? val : 0.2f * val;
    }
  }
}

// one wave per output row; lane-strided dot + shuffle reduce
__global__ __launch_bounds__(256) void head1_kernel(const float* __restrict__ v,
                                                    const float* __restrict__ L1,
                                                    const float* __restrict__ g8,
                                                    const float* __restrict__ b8,
                                                    float* __restrict__ v1) {
  int wave = threadIdx.x >> 6, lane = threadIdx.x & 63;
  int t = blockIdx.x * 4 + wave;   // b*512 + o  (2048)
  int b = t >> 9, o = t & 511;
  const float* vb = v + b * 1152;
  const float* wr = L1 + (long)o * 1152;
  float s = 0.f;
#pragma unroll
  for (int c = lane; c < 1152; c += 64) s = fmaf(wr[c], vb[c], s);
  s = wave_red_sum(s);
  if (lane == 0) {
    float val = fmaf(g8[o] * ISQ, s, b8[o]);
    v1[t] = fmaxf(val, 0.f);
  }
}

__global__ __launch_bounds__(256) void head2_kernel(const float* __restrict__ v1,
                                                    const float* __restrict__ L2,
                                                    const float* __restrict__ L2b,
                                                    const float* __restrict__ g9,
                                                    const float* __restrict__ b9,
                                                    float* __restrict__ v2) {
  int wave = threadIdx.x >> 6, lane = threadIdx.x & 63;
  int t = blockIdx.x * 4 + wave;   // b*256 + o  (1024)
  int b = t >> 8, o = t & 255;
  const float* vb = v1 + b * 512;
  const float* wr = L2 + (long)o * 512;
  float s = 0.f;
#pragma unroll
  for (int c = lane; c < 512; c += 64) s = fmaf(wr[c], vb[c], s);
  s = wave_red_sum(s);
  if (lane == 0) {
    float sv = s + L2b[o];
    float val = fmaf(g9[o] * ISQ, sv, b9[o]);
    v2[t] = fmaxf(val, 0.f);
  }
}

__global__ __launch_bounds__(256) void head3_kernel(const float* __restrict__ v2,
                                                    const float* __restrict__ L3,
                                                    const float* __restrict__ L3b,
                                                    void* __restrict__ out,
                                                    const int* __restrict__ flag) {
  int wave = threadIdx.x >> 6, lane = threadIdx.x & 63;
  int t = blockIdx.x * 4 + wave;   // b*28 + o  (112)
  if (t >= 112) return;
  int b = t / 28, o = t % 28;
  const float* vb = v2 + b * 256;
  const float* wr = L3 + o * 256;
  float s = 0.f;
#pragma unroll
  for (int c = lane; c < 256; c += 64) s = fmaf(wr[c], vb[c], s);
  s = wave_red_sum(s);
  if (lane == 0) {
    float sv = s + L3b[o];
    if (flag[0]) ((__hip_bfloat16*)out)[t] = __float2bfloat16(sv);
    else         ((float*)out)[t] = sv;
  }
}

extern "C" void kernel_launch(void* const* d_in, const int* in_sizes, int n_in,
                              void* d_out, int out_size, void* d_ws, size_t ws_size,
                              hipStream_t stream) {
  CvtArgs ca;
  int off[NIN + 1];
  off[0] = 0;
  for (int i = 0; i < NIN; ++i) {
    ca.src[i] = d_in[i];
    off[i + 1] = off[i] + in_sizes[i];
    ca.off[i] = off[i];
  }
  ca.off[NIN] = off[NIN];
  const int total = off[NIN];

  int* flag = (int*)d_ws;
  float* fin = (float*)((char*)d_ws + 64);
  const float* xf  = fin + off[0];
  const float* lf  = fin + off[1];
  const float* nf  = fin + off[2];
  const float* W1f = fin + off[3];  const float* g1f = fin + off[4];  const float* b1f = fin + off[5];
  const float* W2f = fin + off[6];  const float* g2f = fin + off[7];  const float* b2f_ = fin + off[8];
  const float* W3f = fin + off[9];  const float* g3f = fin + off[10]; const float* b3f = fin + off[11];
  const float* W4f = fin + off[12]; const float* g4f = fin + off[13]; const float* b4f = fin + off[14];
  const float* g5f = fin + off[16]; const float* b5f = fin + off[17];
  const float* W6f = fin + off[18]; const float* g6f = fin + off[19]; const float* b6f = fin + off[20];
  const float* W7f = fin + off[21]; const float* g7f = fin + off[22]; const float* b7f = fin + off[23];
  const float* L1f = fin + off[24]; const float* g8f = fin + off[25]; const float* b8f = fin + off[26];
  const float* L2f = fin + off[27]; const float* L2bf = fin + off[28];
  const float* g9f = fin + off[29]; const float* b9f = fin + off[30];
  const float* L3f = fin + off[31]; const float* L3bf = fin + off[32];

  float* p = fin + ((total + 15) & ~15);
  float* cat  = p;                               // 4*512*2048 (fp32, channel-major)
  float* yb   = cat + 4 * 512 * NPTS;            // 4*2048*256 (point-major)
  float* zb   = yb + 4 * 256 * NPTS;             // 4*2048*256 (point-major)
  float* xxb  = zb + 4 * 256 * NPTS;             // 4*2048
  int*   idxb = (int*)(xxb + 4 * NPTS);          // 4*2048*32
  float* pmax = (float*)(idxb + 4 * NPTS * KNN); // 4*1024*32
  float* vb   = pmax + 4 * 1024 * 32;            // 4*1152
  float* v1b  = vb + 4 * 1152;                   // 4*512
  float* v2b  = v1b + 4 * 512;                   // 4*256
  __hip_bfloat16* w5bf  = (__hip_bfloat16*)(v2b + 4 * 256);           // 1024*512 bf16
  __hip_bfloat16* catbf = w5bf + 1024 * 512;                          // 4*2048*512 bf16
  unsigned* keys_tail = (unsigned*)(catbf + (size_t)4 * NPTS * 512);

  size_t need_full = (size_t)((char*)(keys_tail + (size_t)NB * NPTS * NPTS) - (char*)d_ws);
  int bpass = (ws_size >= need_full) ? NB : 1;
  unsigned* keys = (bpass == NB) ? keys_tail : (unsigned*)yb;

  const long bst1 = 3L * NPTS;
  const long bstc = 512L * NPTS;
  const int NTRI = 32 * 33 / 2;   // 528 triangular 64x64 tiles
  const int nb1 = (total + 255) / 256;
  const int NSEL = NB * 512;      // 2048 select blocks (4 rows each)

  detect_kernel<<<1, 64, 0, stream>>>((const unsigned short*)d_in[0], flag);
  cvt_all_kernel<<<nb1 + 2048 + 32, 256, 0, stream>>>(ca, fin, total, nb1, w5bf, xxb, flag);

  // ---- layer 1: C=3, O=64 — fused in-LDS knn (no keys buffer)
  knn3_kernel<<<dim3(512, NB), 256, 0, stream>>>(xf, xxb, idxb);
  yzt_kernel<3><<<dim3(1, 32, NB), 256, 0, stream>>>(xf, bst1, W1f, 64, yb, zb);
  gmaxt_kernel<1><<<dim3(512, NB), 256, 0, stream>>>(yb, zb, idxb, g1f, b1f, cat, bstc, xxb, catbf, 0);

  // ---- layer 2: C=64, O=64
  if (bpass == NB) {
    pdgemmsym_kernel<64><<<dim3(NTRI, NB), 256, 0, stream>>>(cat, bstc, xxb, keys);
    selyzt_kernel<64, 1><<<NSEL + 1 * 32 * NB, 256, 0, stream>>>(keys, idxb, cat, bstc, W2f, yb, zb, NSEL);
  } else {
    for (int b0 = 0; b0 < NB; b0 += bpass) {
      pdgemmsym_kernel<64><<<dim3(NTRI, bpass), 256, 0, stream>>>(cat + b0 * bstc, bstc, xxb + b0 * NPTS, keys);
      select_kernel<<<512 * bpass, 256, 0, stream>>>(keys, idxb + (long)b0 * NPTS * KNN);
    }
    yzt_kernel<64><<<dim3(1, 32, NB), 256, 0, stream>>>(cat, bstc, W2f, 64, yb, zb);
  }
  gmaxt_kernel<1><<<dim3(512, NB), 256, 0, stream>>>(yb, zb, idxb, g2f, b2f_, cat + 64L * NPTS, bstc, xxb, catbf, 64);

  // ---- layer 3: C=64, O=128
  if (bpass == NB) {
    pdgemmsym_kernel<64><<<dim3(NTRI, NB), 256, 0, stream>>>(cat + 64L * NPTS, bstc, xxb, keys);
    selyzt_kernel<64, 2><<<NSEL + 2 * 32 * NB, 256, 0, stream>>>(keys, idxb, cat + 64L * NPTS, bstc, W3f, yb, zb, NSEL);
  } else {
    for (int b0 = 0; b0 < NB; b0 += bpass) {
      pdgemmsym_kernel<64><<<dim3(NTRI, bpass), 256, 0, stream>>>(cat + 64L * NPTS + b0 * bstc, bstc, xxb + b0 * NPTS, keys);
      select_kernel<<<512 * bpass, 256, 0, stream>>>(keys, idxb + (long)b0 * NPTS * KNN);
    }
    yzt_kernel<64><<<dim3(2, 32, NB), 256, 0, stream>>>(cat + 64L * NPTS, bstc, W3f, 128, yb, zb);
  }
  gmaxt_kernel<2><<<dim3(512, NB), 256, 0, stream>>>(yb, zb, idxb, g3f, b3f, cat + 128L * NPTS, bstc, xxb, catbf, 128);

  // ---- layer 4: C=128, O=256
  if (bpass == NB) {
    pdgemmsym_kernel<128><<<dim3(NTRI, NB), 256, 0, stream>>>(cat + 128L * NPTS, bstc, xxb, keys);
    selyzt_kernel<128, 4><<<NSEL + 4 * 32 * NB, 256, 0, stream>>>(keys, idxb, cat + 128L * NPTS, bstc, W4f, yb, zb, NSEL);
  } else {
    for (int b0 = 0; b0 < NB; b0 += bpass) {
      pdgemmsym_kernel<128><<<dim3(NTRI, bpass), 256, 0, stream>>>(cat + 128L * NPTS + b0 * bstc, bstc, xxb + b0 * NPTS, keys);
      select_kernel<<<512 * bpass, 256, 0, stream>>>(keys, idxb + (long)b0 * NPTS * KNN);
    }
    yzt_kernel<128><<<dim3(4, 32, NB), 256, 0, stream>>>(cat + 128L * NPTS, bstc, W4f, 256, yb, zb);
  }
  gmaxt_kernel<4><<<dim3(512, NB), 256, 0, stream>>>(yb, zb, idxb, g4f, b4f, cat + 256L * NPTS, bstc, (float*)nullptr, catbf, 256);

  // ---- conv5 (bf16 MFMA, LDS-staged B, double-buffered) + BN + leaky + global max
  gemm5m_kernel<<<dim3(32, 8, NB), 256, 0, stream>>>(catbf, w5bf, g5f, b5f, pmax);
  redlfnf_kernel<<<18, 256, 0, stream>>>(pmax, lf, nf, W6f, g6f, b6f, W7f, g7f, b7f, vb);

  head1_kernel<<<512, 256, 0, stream>>>(vb, L1f, g8f, b8f, v1b);
  head2_kernel<<<256, 256, 0, stream>>>(v1b, L2f, L2bf, g9f, b9f, v2b);
  head3_kernel<<<28, 256, 0, stream>>>(v2b, L3f, L3bf, d_out, flag);
}

// Round 17
// 533.945 us; speedup vs baseline: 1.0214x; 1.0046x over previous
//
#include <hip/hip_runtime.h>
#include <hip/hip_bf16.h>

#define NPTS 2048
#define NB 4
#define KNN 32
#define NIN 33

static __device__ __forceinline__ float b2f(__hip_bfloat16 v) { return __bfloat162float(v); }
#define ISQ 0.99999499996875f /* 1/sqrt(1+1e-5) */

typedef __attribute__((ext_vector_type(8))) short short8v;   // 8 bf16 (4 VGPRs)
typedef __attribute__((ext_vector_type(4))) float f32x4;

// monotone order-preserving key for fp32 (no NaNs): a<b  <=>  ordkey(a)<ordkey(b)
static __device__ __forceinline__ unsigned ordkey(float f) {
  unsigned u = __float_as_uint(f);
  return u ^ (unsigned)(((int)u >> 31) | 0x80000000);
}

static __device__ __forceinline__ void loadv(const float* p, float (&d)[1]) { d[0] = *p; }
static __device__ __forceinline__ void loadv(const float* p, float (&d)[2]) {
  float2 v = *(const float2*)p; d[0] = v.x; d[1] = v.y;
}
static __device__ __forceinline__ void loadv(const float* p, float (&d)[4]) {
  float4 v = *(const float4*)p; d[0] = v.x; d[1] = v.y; d[2] = v.z; d[3] = v.w;
}

static __device__ __forceinline__ float wave_red_sum(float s) {
#pragma unroll
  for (int off = 32; off > 0; off >>= 1) s += __shfl_xor(s, off);
  return s;
}

// ---- dtype detect: flag=1 if buffer is bf16, 0 if fp32 ----
__global__ __launch_bounds__(64) void detect_kernel(const unsigned short* __restrict__ x,
                                                    int* __restrict__ flag) {
  int cnt = 0;
  for (int i = threadIdx.x; i < 512; i += 64) {
    unsigned e = (x[i] >> 7) & 0xFFu;
    if (e >= 0xC6u) cnt++;
  }
#pragma unroll
  for (int off = 32; off > 0; off >>= 1) cnt += __shfl_down(cnt, off);
  if (threadIdx.x == 0) flag[0] = (cnt == 0) ? 1 : 0;
}

struct CvtArgs {
  const void* src[NIN];
  int off[NIN + 1];
};

// blocks [0, nb1): convert all inputs into fp32 pool.
// blocks [nb1, nb1+2048): convert W5 to bf16.
// blocks [nb1+2048, +32): xx for layer 1 straight from raw input.
__global__ __launch_bounds__(256) void cvt_all_kernel(CvtArgs a, float* __restrict__ out,
                                                      int total, int nb1,
                                                      __hip_bfloat16* __restrict__ w5bf,
                                                      float* __restrict__ xxb,
                                                      const int* __restrict__ flag) {
  int fl = flag[0];
  if ((int)blockIdx.x < nb1) {
    int t = blockIdx.x * 256 + threadIdx.x;
    if (t >= total) return;
    int s = 0;
    while (t >= a.off[s + 1]) s++;
    int j = t - a.off[s];
    float v;
    if (fl) v = b2f(((const __hip_bfloat16*)a.src[s])[j]);
    else    v = ((const float*)a.src[s])[j];
    out[t] = v;
  } else if ((int)blockIdx.x < nb1 + 2048) {
    int t = (blockIdx.x - nb1) * 256 + threadIdx.x;   // 1024*512
    if (fl) w5bf[t] = ((const __hip_bfloat16*)a.src[15])[t];
    else    w5bf[t] = __float2bfloat16(((const float*)a.src[15])[t]);
  } else {
    int t = (blockIdx.x - nb1 - 2048) * 256 + threadIdx.x;  // b*NPTS + m (8192)
    int b = t >> 11, m = t & 2047;
    float s = 0.f;
#pragma unroll
    for (int c = 0; c < 3; ++c) {
      long o = ((long)b * 3 + c) * NPTS + m;
      float v = fl ? b2f(((const __hip_bfloat16*)a.src[0])[o])
                   : ((const float*)a.src[0])[o];
      s = fmaf(v, v, s);
    }
    xxb[t] = s;
  }
}

// ---- shared select machinery: top-4 prefilter + ballot radix + verify + emission ----
// MODE 0: K[s] holds m = (s>>2)*256 + lane*4 + (s&3)   (uint4 keys layout)
// MODE 1: K[s] holds m = s*64 + lane                    (knn3 in-register layout)
template <int MODE>
static __device__ __forceinline__ int midx(int s, int lane) {
  return MODE == 0 ? (((s >> 2) << 8) + lane * 4 + (s & 3)) : (s * 64 + lane);
}

template <int MODE>
static __device__ __forceinline__ void select_from_K(unsigned (&K)[32], int lane,
                                                     int* __restrict__ orow) {
  unsigned t0 = 0, t1 = 0, t2 = 0, t3 = 0;
#pragma unroll
  for (int s = 0; s < 32; ++s) {
    unsigned k = K[s];
    if (k > t3) {
      if (k > t1) {
        if (k > t0) { t3 = t2; t2 = t1; t1 = t0; t0 = k; }
        else        { t3 = t2; t2 = t1; t1 = k; }
      } else {
        if (k > t2) { t3 = t2; t2 = k; }
        else        { t3 = k; }
      }
    }
  }
  unsigned orv = t0 | t1 | t2 | t3, andv = t0 & t1 & t2 & t3;
#pragma unroll
  for (int xm = 32; xm >= 1; xm >>= 1) {
    orv  |= __shfl_xor(orv, xm);
    andv &= __shfl_xor(andv, xm);
  }
  unsigned V = orv ^ andv;
  unsigned P = andv & ~V;
  int need = KNN;
  for (int b = 31; b >= 0; --b) {
    unsigned bit = 1u << b;
    if (!(V & bit)) continue;
    unsigned hm = 0xFFFFFFFFu << b;
    unsigned Pb = (P & hm) | bit;
    int c = (int)__popcll(__ballot((t0 & hm) == Pb)) +
            (int)__popcll(__ballot((t1 & hm) == Pb)) +
            (int)__popcll(__ballot((t2 & hm) == Pb)) +
            (int)__popcll(__ballot((t3 & hm) == Pb));
    if (c >= need) P |= bit;
    else need -= c;
  }
  int cg = 0;
#pragma unroll
  for (int s = 0; s < 32; ++s) cg += (int)__popcll(__ballot(K[s] > P));
  if (cg > KNN - 1) {
    unsigned orf = K[0], anf = K[0];
#pragma unroll
    for (int s = 1; s < 32; ++s) { orf |= K[s]; anf &= K[s]; }
#pragma unroll
    for (int xm = 32; xm >= 1; xm >>= 1) {
      orf |= __shfl_xor(orf, xm);
      anf &= __shfl_xor(anf, xm);
    }
    unsigned Vf = orf ^ anf;
    P = anf & ~Vf;
    need = KNN;
    for (int b = 31; b >= 0; --b) {
      unsigned bit = 1u << b;
      if (!(Vf & bit)) continue;
      unsigned hm = 0xFFFFFFFFu << b;
      unsigned Pb = (P & hm) | bit;
      int c = 0;
#pragma unroll
      for (int s = 0; s < 32; ++s) c += (int)__popcll(__ballot((K[s] & hm) == Pb));
      if (c >= need) P |= bit;
      else need -= c;
    }
  }
  int base = 0;
  unsigned eqmask = 0;
#pragma unroll
  for (int s = 0; s < 32; ++s) {
    bool take = K[s] > P;
    unsigned long long bal = __ballot(take);
    if (take) {
      int pos = base + (int)__popcll(bal & ((1ull << lane) - 1ull));
      orow[pos] = midx<MODE>(s, lane);
    }
    base += (int)__popcll(bal);
    if (K[s] == P) eqmask |= (1u << s);
  }
  int rem = KNN - base;
  for (int it = 0; it < rem; ++it) {
    unsigned mym = 0xFFFFFFFFu;
    if (eqmask) {
      int s = __ffs(eqmask) - 1;        // per-lane smallest m (m increases with s)
      mym = (unsigned)midx<MODE>(s, lane);
    }
    unsigned wm = mym;
#pragma unroll
    for (int xm = 32; xm >= 1; xm >>= 1) {
      unsigned o = __shfl_xor(wm, xm);
      wm = o < wm ? o : wm;
    }
    if (mym == wm) {
      orow[base + it] = (int)wm;
      eqmask &= eqmask - 1;
    }
  }
}

// ---- knn3 body: fused pd+select for layer 1 (C=3), x+xx staged in LDS ----
static __device__ __forceinline__ void knn3_body(char* smem, const float* __restrict__ xf,
                                                 const float* __restrict__ xxb,
                                                 int* __restrict__ idxout, int b, int nblk) {
  float* xs = (float*)smem;          // [3*NPTS]
  float* xxs = xs + 3 * NPTS;        // [NPTS]
  int tid = threadIdx.x, wave = tid >> 6, lane = tid & 63;
  const float* xb = xf + (long)b * 3 * NPTS;
  for (int i = tid; i < 3 * NPTS; i += 256) xs[i] = xb[i];
  for (int i = tid; i < NPTS; i += 256) xxs[i] = xxb[(b << 11) + i];
  __syncthreads();
  int n = nblk * 4 + wave;
  float q0 = xs[n], q1 = xs[NPTS + n], q2 = xs[2 * NPTS + n];
  float xxn = xxs[n];
  unsigned K[32];
#pragma unroll
  for (int s = 0; s < 32; ++s) {
    int m = s * 64 + lane;
    float d = 0.f;
    d = fmaf(q0, xs[m], d);
    d = fmaf(q1, xs[NPTS + m], d);
    d = fmaf(q2, xs[2 * NPTS + m], d);
    float pdv = (-xxn - (-2.f * d)) - xxs[m];
    K[s] = ordkey(pdv);
  }
  select_from_K<1>(K, lane, idxout + (((b << 11) | n) * KNN));
}

// ---- pd body: 64x64 symmetric tile (triangular id), LDS Ts mirror ----
template <int C>
static __device__ __forceinline__ void pd_body(char* smem, const float* __restrict__ x,
                                               long bstride, const float* __restrict__ xx,
                                               unsigned* __restrict__ keys, int t, int bb) {
  constexpr int KT = (C < 16) ? C : 16;
  float* At = (float*)smem;                  // [KT][64]
  float* Bt = At + KT * 64;                  // [KT][64]
  unsigned* Ts = (unsigned*)(Bt + KT * 64);  // [64][68]
  int tj = (int)((sqrtf(8.f * (float)t + 1.f) - 1.f) * 0.5f);
  while ((tj + 1) * (tj + 2) / 2 <= t) tj++;
  while (tj * (tj + 1) / 2 > t) tj--;
  int ti = t - tj * (tj + 1) / 2;            // ti <= tj
  int n0 = ti * 64, m0 = tj * 64;
  int tid = threadIdx.x, tx = tid & 15, ty = tid >> 4;
  const float* xb = x + (long)bb * bstride;
  float acc[4][4] = {};
  for (int k0 = 0; k0 < C; k0 += KT) {
    for (int lin = tid; lin < KT * 64; lin += 256) {
      int r = lin >> 6, col = lin & 63;
      At[r * 64 + col] = xb[(long)(k0 + r) * NPTS + n0 + col];
      Bt[r * 64 + col] = xb[(long)(k0 + r) * NPTS + m0 + col];
    }
    __syncthreads();
#pragma unroll
    for (int kc = 0; kc < KT; ++kc) {
      float4 av = *(const float4*)&At[kc * 64 + ty * 4];
      float4 bv = *(const float4*)&Bt[kc * 64 + tx * 4];
      acc[0][0] = fmaf(av.x, bv.x, acc[0][0]); acc[0][1] = fmaf(av.x, bv.y, acc[0][1]);
      acc[0][2] = fmaf(av.x, bv.z, acc[0][2]); acc[0][3] = fmaf(av.x, bv.w, acc[0][3]);
      acc[1][0] = fmaf(av.y, bv.x, acc[1][0]); acc[1][1] = fmaf(av.y, bv.y, acc[1][1]);
      acc[1][2] = fmaf(av.y, bv.z, acc[1][2]); acc[1][3] = fmaf(av.y, bv.w, acc[1][3]);
      acc[2][0] = fmaf(av.z, bv.x, acc[2][0]); acc[2][1] = fmaf(av.z, bv.y, acc[2][1]);
      acc[2][2] = fmaf(av.z, bv.z, acc[2][2]); acc[2][3] = fmaf(av.z, bv.w, acc[2][3]);
      acc[3][0] = fmaf(av.w, bv.x, acc[3][0]); acc[3][1] = fmaf(av.w, bv.y, acc[3][1]);
      acc[3][2] = fmaf(av.w, bv.z, acc[3][2]); acc[3][3] = fmaf(av.w, bv.w, acc[3][3]);
    }
    __syncthreads();
  }
  const float* xxq = xx + (long)bb * NPTS;
  float4 xxm = *(const float4*)&xxq[m0 + tx * 4];
  unsigned* kb = keys + ((long)bb << 22);
  unsigned ok[4][4];
#pragma unroll
  for (int i = 0; i < 4; ++i) {
    float xxn = xxq[n0 + ty * 4 + i];
    ok[i][0] = ordkey((-xxn - (-2.f * acc[i][0])) - xxm.x);
    ok[i][1] = ordkey((-xxn - (-2.f * acc[i][1])) - xxm.y);
    ok[i][2] = ordkey((-xxn - (-2.f * acc[i][2])) - xxm.z);
    ok[i][3] = ordkey((-xxn - (-2.f * acc[i][3])) - xxm.w);
    uint4 o = make_uint4(ok[i][0], ok[i][1], ok[i][2], ok[i][3]);
    *(uint4*)&kb[(long)(n0 + ty * 4 + i) * NPTS + m0 + tx * 4] = o;
  }
  if (ti != tj) {
#pragma unroll
    for (int i = 0; i < 4; ++i)
#pragma unroll
      for (int j = 0; j < 4; ++j) Ts[(tx * 4 + j) * 68 + ty * 4 + i] = ok[i][j];
    __syncthreads();
#pragma unroll
    for (int i = 0; i < 4; ++i)
      *(uint4*)&kb[(long)(m0 + ty * 4 + i) * NPTS + n0 + tx * 4] =
          *(const uint4*)&Ts[(ty * 4 + i) * 68 + tx * 4];
  }
}

// ---- yzt body: point-major GEMM, yt[b][m][o], zt[b][m][o] ----
template <int C>
static __device__ __forceinline__ void yzt_body(char* smem, const float* __restrict__ x,
                                                long bstride, const float* __restrict__ W, int O,
                                                float* __restrict__ yt, float* __restrict__ zt,
                                                int b, int m0, int o0) {
  constexpr int KT = (C < 16) ? C : 16;
  float* Xs = (float*)smem;        // [KT][64]
  float* Wy = Xs + KT * 64;        // [KT][64]
  float* Wp = Wy + KT * 64;        // [KT][64]
  int tid = threadIdx.x, tx = tid & 15, ty = tid >> 4;
  const float* xb = x + (long)b * bstride;
  const int twoC = 2 * C;
  float accy[4][4] = {}, accp[4][4] = {};
  for (int k0 = 0; k0 < C; k0 += KT) {
    for (int lin = tid; lin < KT * 64; lin += 256) {
      int r = lin >> 6, col = lin & 63;
      Xs[r * 64 + col] = xb[(long)(k0 + r) * NPTS + m0 + col];
      float wy = W[(o0 + col) * twoC + k0 + r];
      Wy[r * 64 + col] = wy;
      Wp[r * 64 + col] = W[(o0 + col) * twoC + C + k0 + r] - wy;
    }
    __syncthreads();
#pragma unroll
    for (int kc = 0; kc < KT; ++kc) {
      float4 wv = *(const float4*)&Wy[kc * 64 + tx * 4];
      float4 pv = *(const float4*)&Wp[kc * 64 + tx * 4];
      float xm[4];
      xm[0] = Xs[kc * 64 + ty * 4 + 0]; xm[1] = Xs[kc * 64 + ty * 4 + 1];
      xm[2] = Xs[kc * 64 + ty * 4 + 2]; xm[3] = Xs[kc * 64 + ty * 4 + 3];
#pragma unroll
      for (int i = 0; i < 4; ++i) {
        accy[i][0] = fmaf(xm[i], wv.x, accy[i][0]);
        accy[i][1] = fmaf(xm[i], wv.y, accy[i][1]);
        accy[i][2] = fmaf(xm[i], wv.z, accy[i][2]);
        accy[i][3] = fmaf(xm[i], wv.w, accy[i][3]);
        accp[i][0] = fmaf(xm[i], pv.x, accp[i][0]);
        accp[i][1] = fmaf(xm[i], pv.y, accp[i][1]);
        accp[i][2] = fmaf(xm[i], pv.z, accp[i][2]);
        accp[i][3] = fmaf(xm[i], pv.w, accp[i][3]);
      }
    }
    __syncthreads();
  }
#pragma unroll
  for (int i = 0; i < 4; ++i) {
    long base = ((long)b * NPTS + m0 + ty * 4 + i) * O + o0 + tx * 4;
    *(float4*)&yt[base] = make_float4(accy[i][0], accy[i][1], accy[i][2], accy[i][3]);
    *(float4*)&zt[base] = make_float4(accp[i][0], accp[i][1], accp[i][2], accp[i][3]);
  }
}

// ---- select body (keys layout) ----
static __device__ __forceinline__ void select_body(const unsigned* __restrict__ keys,
                                                   int* __restrict__ idxout, int q) {
  int lane = threadIdx.x & 63;
  int bloc = q >> 11, n = q & 2047;
  const uint4* rp = (const uint4*)(keys + ((long)((bloc << 11) | n) << 11));
  unsigned K[32];
#pragma unroll
  for (int t = 0; t < 8; ++t) {
    uint4 kk = rp[t * 64 + lane];
    K[4 * t + 0] = kk.x; K[4 * t + 1] = kk.y; K[4 * t + 2] = kk.z; K[4 * t + 3] = kk.w;
  }
  select_from_K<0>(K, lane, idxout + ((bloc << 11) | n) * KNN);
}

// fused select || yzt, INTERLEAVED: every K-th block (c<nyzt) is yzt, rest select.
template <int C, int O64>
__global__ __launch_bounds__(256) void selyzt_kernel(const unsigned* __restrict__ keys,
                                                     int* __restrict__ idxout,
                                                     const float* __restrict__ x, long bstride,
                                                     const float* __restrict__ W,
                                                     float* __restrict__ yt,
                                                     float* __restrict__ zt, int K, int nyzt) {
  constexpr int KT = (C < 16) ? C : 16;
  __shared__ __align__(16) char smem[(size_t)KT * 64 * 3 * 4];
  int bid = blockIdx.x;
  int c = bid / K, r = bid - c * K;
  if (r == 0 && c < nyzt) {
    int rem = c;                         // o64 * (32*NB) + my*NB + b
    int b = rem % NB; rem /= NB;
    int m0 = (rem % 32) * 64; rem /= 32;
    int o0 = rem * 64;
    yzt_body<C>(smem, x, bstride, W, O64 * 64, yt, zt, b, m0, o0);
  } else {
    int sid = (c < nyzt) ? (c * (K - 1) + r - 1) : (bid - nyzt);
    int wave = threadIdx.x >> 6;
    select_body(keys, idxout, sid * 4 + wave);
  }
}

// fused knn3 || yzt<3>, INTERLEAVED (layer 1)
__global__ __launch_bounds__(256) void knn3yzt_kernel(const float* __restrict__ xf,
                                                      const float* __restrict__ xxb,
                                                      int* __restrict__ idxout,
                                                      const float* __restrict__ W1,
                                                      float* __restrict__ yt,
                                                      float* __restrict__ zt, int K, int nyzt) {
  __shared__ __align__(16) char smem[4 * NPTS * 4];   // 32 KB (knn3 arena; yzt<3> uses prefix)
  int bid = blockIdx.x;
  int c = bid / K, r = bid - c * K;
  if (r == 0 && c < nyzt) {
    int b = c % NB;
    int m0 = ((c / NB) % 32) * 64;
    yzt_body<3>(smem, xf, 3L * NPTS, W1, 64, yt, zt, b, m0, 0);
  } else {
    int sid = (c < nyzt) ? (c * (K - 1) + r - 1) : (bid - nyzt);
    knn3_body(smem, xf, xxb, idxout, sid >> 9, sid & 511);
  }
}

// standalone kernels (fallback path)
__global__ __launch_bounds__(256) void select_kernel(const unsigned* __restrict__ keys,
                                                     int* __restrict__ idxout) {
  int wave = threadIdx.x >> 6;
  select_body(keys, idxout, blockIdx.x * 4 + wave);
}

template <int C>
__global__ __launch_bounds__(256) void pdgemmsym_kernel(const float* __restrict__ x, long bstride,
                                                        const float* __restrict__ xx,
                                                        unsigned* __restrict__ keys) {
  constexpr int KT = (C < 16) ? C : 16;
  constexpr size_t SM = (size_t)KT * 64 * 2 * 4 + 64 * 68 * 4;
  __shared__ __align__(16) char smem[SM];
  pd_body<C>(smem, x, bstride, xx, keys, blockIdx.x, blockIdx.y);
}

template <int C>
__global__ __launch_bounds__(256) void yzt_kernel(const float* __restrict__ x, long bstride,
                                                  const float* __restrict__ W, int O,
                                                  float* __restrict__ yt, float* __restrict__ zt) {
  constexpr int KT = (C < 16) ? C : 16;
  constexpr size_t SM = (size_t)KT * 64 * 3 * 4;
  __shared__ __align__(16) char smem[SM];
  yzt_body<C>(smem, x, bstride, W, O, yt, zt, blockIdx.z, blockIdx.y * 64, blockIdx.x * 64);
}

// gmaxt: one wave per query n; emits xx for next layer + bf16 point-major cat copy
template <int RO>
__global__ __launch_bounds__(256) void gmaxt_kernel(const float* __restrict__ yt,
                                                    const float* __restrict__ zt,
                                                    const int* __restrict__ idx,
                                                    const float* __restrict__ g,
                                                    const float* __restrict__ bb,
                                                    float* __restrict__ out, long obstride,
                                                    float* __restrict__ xxout,
                                                    __hip_bfloat16* __restrict__ catbf, int loff) {
  constexpr int O = RO * 64;
  int wave = threadIdx.x >> 6, lane = threadIdx.x & 63;
  int n = blockIdx.x * 4 + wave, b = blockIdx.y;
  int jreg = idx[((b << 11) + n) * KNN + (lane & 31)];
  int obase = lane * RO;
  float gs[RO], bs[RO], zr[RO], acc[RO];
  loadv(zt + ((long)(b << 11) + n) * O + obase, zr);
#pragma unroll
  for (int r = 0; r < RO; ++r) {
    gs[r] = g[obase + r] * ISQ;
    bs[r] = bb[obase + r];
    acc[r] = -INFINITY;
  }
  const float* yb = yt + ((long)(b << 11)) * O + obase;
#pragma unroll
  for (int k = 0; k < KNN; ++k) {
    int j = __shfl(jreg, k);
    float yv[RO];
    loadv(yb + (long)j * O, yv);
#pragma unroll
    for (int r = 0; r < RO; ++r) {
      float v = fmaf(gs[r], yv[r] + zr[r], bs[r]);
      v = v >= 0.f ? v : 0.2f * v;
      acc[r] = fmaxf(acc[r], v);
    }
  }
  float* op = out + (long)b * obstride + (long)obase * NPTS + n;
#pragma unroll
  for (int r = 0; r < RO; ++r) op[(long)r * NPTS] = acc[r];
  __hip_bfloat16* cb = catbf + ((long)(b << 11) + n) * 512 + loff + obase;
#pragma unroll
  for (int r = 0; r < RO; ++r) cb[r] = __float2bfloat16(acc[r]);
  if (xxout) {
    float ss = 0.f;
#pragma unroll
    for (int r = 0; r < RO; ++r) ss = fmaf(acc[r], acc[r], ss);
    ss = wave_red_sum(ss);
    if (lane == 0) xxout[(b << 11) + n] = ss;
  }
}

// MFMA W5 GEMM + BN + leaky + 64n partial max. LDS-staged B, double-buffered.
__global__ __launch_bounds__(256) void gemm5m_kernel(const __hip_bfloat16* __restrict__ catbf,
                                                     const __hip_bfloat16* __restrict__ w5bf,
                                                     const float* __restrict__ g5,
                                                     const float* __restrict__ b5,
                                                     float* __restrict__ pmax) {
  __shared__ __align__(16) short Bs[2][8 * 64 * 8];
  int b = blockIdx.z, po0 = blockIdx.y * 128, n0 = blockIdx.x * 64;
  int wave = threadIdx.x >> 6, lane = threadIdx.x & 63;
  int quad = lane >> 4, l15 = lane & 15;
  const short* cbase = (const short*)catbf + ((long)(b << 11) + n0) * 512;
  const short* abase0 = (const short*)w5bf + (long)(po0 + wave * 32 + l15) * 512 + quad * 8;
  const short* abase1 = abase0 + 16 * 512;
  const short* bsrc0 = cbase + (long)lane * 512 + (2 * wave + 0) * 8;
  const short* bsrc1 = cbase + (long)lane * 512 + (2 * wave + 1) * 8;
  short* bdst0 = &Bs[0][((2 * wave + 0) * 64 + lane) * 8];
  short* bdst1 = &Bs[0][((2 * wave + 1) * 64 + lane) * 8];
  const int bufstride = 8 * 64 * 8;

  short8v Br[2][2], Ar[2][2][2];
  f32x4 acc[2][4] = {};

  Br[0][0] = *(const short8v*)(bsrc0);
  Br[0][1] = *(const short8v*)(bsrc1);
#pragma unroll
  for (int h = 0; h < 2; ++h)
#pragma unroll
    for (int j = 0; j < 2; ++j)
      Ar[0][h][j] = *(const short8v*)((h ? abase1 : abase0) + j * 32);
  *(short8v*)bdst0 = Br[0][0];
  *(short8v*)bdst1 = Br[0][1];
  Br[1][0] = *(const short8v*)(bsrc0 + 64);
  Br[1][1] = *(const short8v*)(bsrc1 + 64);
#pragma unroll
  for (int h = 0; h < 2; ++h)
#pragma unroll
    for (int j = 0; j < 2; ++j)
      Ar[1][h][j] = *(const short8v*)((h ? abase1 : abase0) + 64 + j * 32);
  __syncthreads();

  for (int it = 0; it < 8; ++it) {
    int cur = it & 1;
    const short* lb = &Bs[cur][0];
#pragma unroll
    for (int j = 0; j < 2; ++j) {
#pragma unroll
      for (int nt = 0; nt < 4; ++nt) {
        short8v bf = *(const short8v*)(lb + ((j * 4 + quad) * 64 + nt * 16 + l15) * 8);
        acc[0][nt] = __builtin_amdgcn_mfma_f32_16x16x32_bf16(Ar[cur][0][j], bf, acc[0][nt], 0, 0, 0);
        acc[1][nt] = __builtin_amdgcn_mfma_f32_16x16x32_bf16(Ar[cur][1][j], bf, acc[1][nt], 0, 0, 0);
      }
    }
    if (it < 7) {
      if (it < 6) {
        int ks = (it + 2) * 64;
        Br[cur][0] = *(const short8v*)(bsrc0 + ks);
        Br[cur][1] = *(const short8v*)(bsrc1 + ks);
#pragma unroll
        for (int h = 0; h < 2; ++h)
#pragma unroll
          for (int j = 0; j < 2; ++j)
            Ar[cur][h][j] = *(const short8v*)((h ? abase1 : abase0) + ks + j * 32);
      }
      int nb = cur ^ 1;
      *(short8v*)(bdst0 + nb * bufstride) = Br[nb][0];
      *(short8v*)(bdst1 + nb * bufstride) = Br[nb][1];
      __syncthreads();
    }
  }

#pragma unroll
  for (int h = 0; h < 2; ++h) {
#pragma unroll
    for (int r = 0; r < 4; ++r) {
      int po = po0 + wave * 32 + h * 16 + quad * 4 + r;
      float sc = g5[po] * ISQ;
      float bi = b5[po];
      float mx = -INFINITY;
#pragma unroll
      for (int nt = 0; nt < 4; ++nt) {
        float v = fmaf(sc, acc[h][nt][r], bi);
        v = v >= 0.f ? v : 0.2f * v;
        mx = fmaxf(mx, v);
      }
#pragma unroll
      for (int xm = 1; xm < 16; xm <<= 1) mx = fmaxf(mx, __shfl_xor(mx, xm));
      if (l15 == 0) pmax[(long)(b * 1024 + po) * 32 + blockIdx.x] = mx;
    }
  }
}

// merged: blocks 0..15 -> global-max reduce of pmax into v; blocks 16..17 -> lf/nf
__global__ __launch_bounds__(256) void redlfnf_kernel(const float* __restrict__ pmax,
                                                      const float* __restrict__ l,
                                                      const float* __restrict__ nn,
                                                      const float* __restrict__ W6,
                                                      const float* __restrict__ g6,
                                                      const float* __restrict__ b6,
                                                      const float* __restrict__ W7,
                                                      const float* __restrict__ g7,
                                                      const float* __restrict__ b7,
                                                      float* __restrict__ v) {
  if (blockIdx.x < 16) {
    int t = blockIdx.x * 256 + threadIdx.x;   // b*1024 + po  (4096)
    float mx = -INFINITY;
#pragma unroll
    for (int j = 0; j < 32; ++j) mx = fmaxf(mx, pmax[(long)t * 32 + j]);
    int b = t >> 10, po = t & 1023;
    v[b * 1152 + po] = mx;
  } else {
    int idx = (blockIdx.x - 16) * 256 + threadIdx.x;  // 512 work items
    int b = idx >> 7, t = idx & 127;
    if (t < 64) {
      float s = 0.f;
#pragma unroll
      for (int c = 0; c < 5; ++c) s = fmaf(W6[t * 5 + c], l[b * 5 + c], s);
      float val = fmaf(g6[t] * ISQ, s, b6[t]);
      v[b * 1152 + 1024 + t] = val >= 0.f ? val : 0.2f * val;
    } else {
      int o = t - 64;
      float s = 0.f;
#pragma unroll
      for (int c = 0; c < 7; ++c) s = fmaf(W7[o * 7 + c], nn[b * 7 + c], s);
      float val = fmaf(g7[o] * ISQ, s, b7[o]);
      v[b * 1152 + 1088 + o] = val >= 0.f ? val : 0.2f * val;
    }
  }
}

// one wave per output row; lane-strided dot + shuffle reduce
__global__ __launch_bounds__(256) void head1_kernel(const float* __restrict__ v,
                                                    const float* __restrict__ L1,
                                                    const float* __restrict__ g8,
                                                    const float* __restrict__ b8,
                                                    float* __restrict__ v1) {
  int wave = threadIdx.x >> 6, lane = threadIdx.x & 63;
  int t = blockIdx.x * 4 + wave;   // b*512 + o  (2048)
  int b = t >> 9, o = t & 511;
  const float* vb = v + b * 1152;
  const float* wr = L1 + (long)o * 1152;
  float s = 0.f;
#pragma unroll
  for (int c = lane; c < 1152; c += 64) s = fmaf(wr[c], vb[c], s);
  s = wave_red_sum(s);
  if (lane == 0) {
    float val = fmaf(g8[o] * ISQ, s, b8[o]);
    v1[t] = fmaxf(val, 0.f);
  }
}

__global__ __launch_bounds__(256) void head2_kernel(const float* __restrict__ v1,
                                                    const float* __restrict__ L2,
                                                    const float* __restrict__ L2b,
                                                    const float* __restrict__ g9,
                                                    const float* __restrict__ b9,
                                                    float* __restrict__ v2) {
  int wave = threadIdx.x >> 6, lane = threadIdx.x & 63;
  int t = blockIdx.x * 4 + wave;   // b*256 + o  (1024)
  int b = t >> 8, o = t & 255;
  const float* vb = v1 + b * 512;
  const float* wr = L2 + (long)o * 512;
  float s = 0.f;
#pragma unroll
  for (int c = lane; c < 512; c += 64) s = fmaf(wr[c], vb[c], s);
  s = wave_red_sum(s);
  if (lane == 0) {
    float sv = s + L2b[o];
    float val = fmaf(g9[o] * ISQ, sv, b9[o]);
    v2[t] = fmaxf(val, 0.f);
  }
}

__global__ __launch_bounds__(256) void head3_kernel(const float* __restrict__ v2,
                                                    const float* __restrict__ L3,
                                                    const float* __restrict__ L3b,
                                                    void* __restrict__ out,
                                                    const int* __restrict__ flag) {
  int wave = threadIdx.x >> 6, lane = threadIdx.x & 63;
  int t = blockIdx.x * 4 + wave;   // b*28 + o  (112)
  if (t >= 112) return;
  int b = t / 28, o = t % 28;
  const float* vb = v2 + b * 256;
  const float* wr = L3 + o * 256;
  float s = 0.f;
#pragma unroll
  for (int c = lane; c < 256; c += 64) s = fmaf(wr[c], vb[c], s);
  s = wave_red_sum(s);
  if (lane == 0) {
    float sv = s + L3b[o];
    if (flag[0]) ((__hip_bfloat16*)out)[t] = __float2bfloat16(sv);
    else         ((float*)out)[t] = sv;
  }
}

extern "C" void kernel_launch(void* const* d_in, const int* in_sizes, int n_in,
                              void* d_out, int out_size, void* d_ws, size_t ws_size,
                              hipStream_t stream) {
  CvtArgs ca;
  int off[NIN + 1];
  off[0] = 0;
  for (int i = 0; i < NIN; ++i) {
    ca.src[i] = d_in[i];
    off[i + 1] = off[i] + in_sizes[i];
    ca.off[i] = off[i];
  }
  ca.off[NIN] = off[NIN];
  const int total = off[NIN];

  int* flag = (int*)d_ws;
  float* fin = (float*)((char*)d_ws + 64);
  const float* xf  = fin + off[0];
  const float* lf  = fin + off[1];
  const float* nf  = fin + off[2];
  const float* W1f = fin + off[3];  const float* g1f = fin + off[4];  const float* b1f = fin + off[5];
  const float* W2f = fin + off[6];  const float* g2f = fin + off[7];  const float* b2f_ = fin + off[8];
  const float* W3f = fin + off[9];  const float* g3f = fin + off[10]; const float* b3f = fin + off[11];
  const float* W4f = fin + off[12]; const float* g4f = fin + off[13]; const float* b4f = fin + off[14];
  const float* g5f = fin + off[16]; const float* b5f = fin + off[17];
  const float* W6f = fin + off[18]; const float* g6f = fin + off[19]; const float* b6f = fin + off[20];
  const float* W7f = fin + off[21]; const float* g7f = fin + off[22]; const float* b7f = fin + off[23];
  const float* L1f = fin + off[24]; const float* g8f = fin + off[25]; const float* b8f = fin + off[26];
  const float* L2f = fin + off[27]; const float* L2bf = fin + off[28];
  const float* g9f = fin + off[29]; const float* b9f = fin + off[30];
  const float* L3f = fin + off[31]; const float* L3bf = fin + off[32];

  float* p = fin + ((total + 15) & ~15);
  float* cat  = p;                               // 4*512*2048 (fp32, channel-major)
  float* yb   = cat + 4 * 512 * NPTS;            // 4*2048*256 (point-major)
  float* zb   = yb + 4 * 256 * NPTS;             // 4*2048*256 (point-major)
  float* xxb  = zb + 4 * 256 * NPTS;             // 4*2048
  int*   idxb = (int*)(xxb + 4 * NPTS);          // 4*2048*32
  float* pmax = (float*)(idxb + 4 * NPTS * KNN); // 4*1024*32
  float* vb   = pmax + 4 * 1024 * 32;            // 4*1152
  float* v1b  = vb + 4 * 1152;                   // 4*512
  float* v2b  = v1b + 4 * 512;                   // 4*256
  __hip_bfloat16* w5bf  = (__hip_bfloat16*)(v2b + 4 * 256);           // 1024*512 bf16
  __hip_bfloat16* catbf = w5bf + 1024 * 512;                          // 4*2048*512 bf16
  unsigned* keys_tail = (unsigned*)(catbf + (size_t)4 * NPTS * 512);

  size_t need_full = (size_t)((char*)(keys_tail + (size_t)NB * NPTS * NPTS) - (char*)d_ws);
  int bpass = (ws_size >= need_full) ? NB : 1;
  unsigned* keys = (bpass == NB) ? keys_tail : (unsigned*)yb;

  const long bst1 = 3L * NPTS;
  const long bstc = 512L * NPTS;
  const int NTRI = 32 * 33 / 2;   // 528 triangular 64x64 tiles
  const int nb1 = (total + 255) / 256;
  const int NSEL = NB * 512;      // 2048 select blocks (4 rows each)

  detect_kernel<<<1, 64, 0, stream>>>((const unsigned short*)d_in[0], flag);
  cvt_all_kernel<<<nb1 + 2048 + 32, 256, 0, stream>>>(ca, fin, total, nb1, w5bf, xxb, flag);

  // ---- layer 1: C=3, O=64 — fused in-LDS knn || yzt (interleaved)
  {
    int nyzt = 32 * NB;                         // 128
    int tot = NSEL + nyzt;                      // 2176
    knn3yzt_kernel<<<tot, 256, 0, stream>>>(xf, xxb, idxb, W1f, yb, zb, tot / nyzt, nyzt);
  }
  gmaxt_kernel<1><<<dim3(512, NB), 256, 0, stream>>>(yb, zb, idxb, g1f, b1f, cat, bstc, xxb, catbf, 0);

  // ---- layer 2: C=64, O=64
  if (bpass == NB) {
    pdgemmsym_kernel<64><<<dim3(NTRI, NB), 256, 0, stream>>>(cat, bstc, xxb, keys);
    int nyzt = 1 * 32 * NB, tot = NSEL + nyzt;
    selyzt_kernel<64, 1><<<tot, 256, 0, stream>>>(keys, idxb, cat, bstc, W2f, yb, zb, tot / nyzt, nyzt);
  } else {
    for (int b0 = 0; b0 < NB; b0 += bpass) {
      pdgemmsym_kernel<64><<<dim3(NTRI, bpass), 256, 0, stream>>>(cat + b0 * bstc, bstc, xxb + b0 * NPTS, keys);
      select_kernel<<<512 * bpass, 256, 0, stream>>>(keys, idxb + (long)b0 * NPTS * KNN);
    }
    yzt_kernel<64><<<dim3(1, 32, NB), 256, 0, stream>>>(cat, bstc, W2f, 64, yb, zb);
  }
  gmaxt_kernel<1><<<dim3(512, NB), 256, 0, stream>>>(yb, zb, idxb, g2f, b2f_, cat + 64L * NPTS, bstc, xxb, catbf, 64);

  // ---- layer 3: C=64, O=128
  if (bpass == NB) {
    pdgemmsym_kernel<64><<<dim3(NTRI, NB), 256, 0, stream>>>(cat + 64L * NPTS, bstc, xxb, keys);
    int nyzt = 2 * 32 * NB, tot = NSEL + nyzt;
    selyzt_kernel<64, 2><<<tot, 256, 0, stream>>>(keys, idxb, cat + 64L * NPTS, bstc, W3f, yb, zb, tot / nyzt, nyzt);
  } else {
    for (int b0 = 0; b0 < NB; b0 += bpass) {
      pdgemmsym_kernel<64><<<dim3(NTRI, bpass), 256, 0, stream>>>(cat + 64L * NPTS + b0 * bstc, bstc, xxb + b0 * NPTS, keys);
      select_kernel<<<512 * bpass, 256, 0, stream>>>(keys, idxb + (long)b0 * NPTS * KNN);
    }
    yzt_kernel<64><<<dim3(2, 32, NB), 256, 0, stream>>>(cat + 64L * NPTS, bstc, W3f, 128, yb, zb);
  }
  gmaxt_kernel<2><<<dim3(512, NB), 256, 0, stream>>>(yb, zb, idxb, g3f, b3f, cat + 128L * NPTS, bstc, xxb, catbf, 128);

  // ---- layer 4: C=128, O=256
  if (bpass == NB) {
    pdgemmsym_kernel<128><<<dim3(NTRI, NB), 256, 0, stream>>>(cat + 128L * NPTS, bstc, xxb, keys);
    int nyzt = 4 * 32 * NB, tot = NSEL + nyzt;
    selyzt_kernel<128, 4><<<tot, 256, 0, stream>>>(keys, idxb, cat + 128L * NPTS, bstc, W4f, yb, zb, tot / nyzt, nyzt);
  } else {
    for (int b0 = 0; b0 < NB; b0 += bpass) {
      pdgemmsym_kernel<128><<<dim3(NTRI, bpass), 256, 0, stream>>>(cat + 128L * NPTS + b0 * bstc, bstc, xxb + b0 * NPTS, keys);
      select_kernel<<<512 * bpass, 256, 0, stream>>>(keys, idxb + (long)b0 * NPTS * KNN);
    }
    yzt_kernel<128><<<dim3(4, 32, NB), 256, 0, stream>>>(cat + 128L * NPTS, bstc, W4f, 256, yb, zb);
  }
  gmaxt_kernel<4><<<dim3(512, NB), 256, 0, stream>>>(yb, zb, idxb, g4f, b4f, cat + 256L * NPTS, bstc, (float*)nullptr, catbf, 256);

  // ---- conv5 (bf16 MFMA, LDS-staged B, double-buffered) + BN + leaky + global max
  gemm5m_kernel<<<dim3(32, 8, NB), 256, 0, stream>>>(catbf, w5bf, g5f, b5f, pmax);
  redlfnf_kernel<<<18, 256, 0, stream>>>(pmax, lf, nf, W6f, g6f, b6f, W7f, g7f, b7f, vb);

  head1_kernel<<<512, 256, 0, stream>>>(vb, L1f, g8f, b8f, v1b);
  head2_kernel<<<256, 256, 0, stream>>>(v1b, L2f, L2bf, g9f, b9f, v2b);
  head3_kernel<<<28, 256, 0, stream>>>(v2b, L3f, L3bf, d_out, flag);
}

// Round 18
// 529.444 us; speedup vs baseline: 1.0300x; 1.0085x over previous
//
#include <hip/hip_runtime.h>
#include <hip/hip_bf16.h>

#define NPTS 2048
#define NB 4
#define KNN 32
#define NIN 33

static __device__ __forceinline__ float b2f(__hip_bfloat16 v) { return __bfloat162float(v); }
#define ISQ 0.99999499996875f /* 1/sqrt(1+1e-5) */

typedef __attribute__((ext_vector_type(8))) short short8v;   // 8 bf16 (4 VGPRs)
typedef __attribute__((ext_vector_type(4))) float f32x4;
typedef __attribute__((ext_vector_type(4))) unsigned uint4v;

// monotone order-preserving key for fp32 (no NaNs): a<b  <=>  ordkey(a)<ordkey(b)
static __device__ __forceinline__ unsigned ordkey(float f) {
  unsigned u = __float_as_uint(f);
  return u ^ (unsigned)(((int)u >> 31) | 0x80000000);
}

static __device__ __forceinline__ void loadv(const float* p, float (&d)[1]) { d[0] = *p; }
static __device__ __forceinline__ void loadv(const float* p, float (&d)[2]) {
  float2 v = *(const float2*)p; d[0] = v.x; d[1] = v.y;
}
static __device__ __forceinline__ void loadv(const float* p, float (&d)[4]) {
  float4 v = *(const float4*)p; d[0] = v.x; d[1] = v.y; d[2] = v.z; d[3] = v.w;
}

static __device__ __forceinline__ float wave_red_sum(float s) {
#pragma unroll
  for (int off = 32; off > 0; off >>= 1) s += __shfl_xor(s, off);
  return s;
}

// ---- dtype detect: flag=1 if buffer is bf16, 0 if fp32 ----
__global__ __launch_bounds__(64) void detect_kernel(const unsigned short* __restrict__ x,
                                                    int* __restrict__ flag) {
  int cnt = 0;
  for (int i = threadIdx.x; i < 512; i += 64) {
    unsigned e = (x[i] >> 7) & 0xFFu;
    if (e >= 0xC6u) cnt++;
  }
#pragma unroll
  for (int off = 32; off > 0; off >>= 1) cnt += __shfl_down(cnt, off);
  if (threadIdx.x == 0) flag[0] = (cnt == 0) ? 1 : 0;
}

struct CvtArgs {
  const void* src[NIN];
  int off[NIN + 1];
};

// blocks [0, nb1): convert all inputs into fp32 pool.
// blocks [nb1, nb1+2048): convert W5 to bf16.
// blocks [nb1+2048, +32): xx for layer 1 straight from raw input.
__global__ __launch_bounds__(256) void cvt_all_kernel(CvtArgs a, float* __restrict__ out,
                                                      int total, int nb1,
                                                      __hip_bfloat16* __restrict__ w5bf,
                                                      float* __restrict__ xxb,
                                                      const int* __restrict__ flag) {
  int fl = flag[0];
  if ((int)blockIdx.x < nb1) {
    int t = blockIdx.x * 256 + threadIdx.x;
    if (t >= total) return;
    int s = 0;
    while (t >= a.off[s + 1]) s++;
    int j = t - a.off[s];
    float v;
    if (fl) v = b2f(((const __hip_bfloat16*)a.src[s])[j]);
    else    v = ((const float*)a.src[s])[j];
    out[t] = v;
  } else if ((int)blockIdx.x < nb1 + 2048) {
    int t = (blockIdx.x - nb1) * 256 + threadIdx.x;   // 1024*512
    if (fl) w5bf[t] = ((const __hip_bfloat16*)a.src[15])[t];
    else    w5bf[t] = __float2bfloat16(((const float*)a.src[15])[t]);
  } else {
    int t = (blockIdx.x - nb1 - 2048) * 256 + threadIdx.x;  // b*NPTS + m (8192)
    int b = t >> 11, m = t & 2047;
    float s = 0.f;
#pragma unroll
    for (int c = 0; c < 3; ++c) {
      long o = ((long)b * 3 + c) * NPTS + m;
      float v = fl ? b2f(((const __hip_bfloat16*)a.src[0])[o])
                   : ((const float*)a.src[0])[o];
      s = fmaf(v, v, s);
    }
    xxb[t] = s;
  }
}

// ---- shared select machinery: top-4 prefilter + ballot radix + verify + emission ----
// MODE 0: K[s] holds m = (s>>2)*256 + lane*4 + (s&3)   (uint4 keys layout)
// MODE 1: K[s] holds m = s*64 + lane                    (knn3 in-register layout)
template <int MODE>
static __device__ __forceinline__ int midx(int s, int lane) {
  return MODE == 0 ? (((s >> 2) << 8) + lane * 4 + (s & 3)) : (s * 64 + lane);
}

template <int MODE>
static __device__ __forceinline__ void select_from_K(unsigned (&K)[32], int lane,
                                                     int* __restrict__ orow) {
  unsigned t0 = 0, t1 = 0, t2 = 0, t3 = 0;
#pragma unroll
  for (int s = 0; s < 32; ++s) {
    unsigned k = K[s];
    if (k > t3) {
      if (k > t1) {
        if (k > t0) { t3 = t2; t2 = t1; t1 = t0; t0 = k; }
        else        { t3 = t2; t2 = t1; t1 = k; }
      } else {
        if (k > t2) { t3 = t2; t2 = k; }
        else        { t3 = k; }
      }
    }
  }
  unsigned orv = t0 | t1 | t2 | t3, andv = t0 & t1 & t2 & t3;
#pragma unroll
  for (int xm = 32; xm >= 1; xm >>= 1) {
    orv  |= __shfl_xor(orv, xm);
    andv &= __shfl_xor(andv, xm);
  }
  unsigned V = orv ^ andv;
  unsigned P = andv & ~V;
  int need = KNN;
  for (int b = 31; b >= 0; --b) {
    unsigned bit = 1u << b;
    if (!(V & bit)) continue;
    unsigned hm = 0xFFFFFFFFu << b;
    unsigned Pb = (P & hm) | bit;
    int c = (int)__popcll(__ballot((t0 & hm) == Pb)) +
            (int)__popcll(__ballot((t1 & hm) == Pb)) +
            (int)__popcll(__ballot((t2 & hm) == Pb)) +
            (int)__popcll(__ballot((t3 & hm) == Pb));
    if (c >= need) P |= bit;
    else need -= c;
  }
  int cg = 0;
#pragma unroll
  for (int s = 0; s < 32; ++s) cg += (int)__popcll(__ballot(K[s] > P));
  if (cg > KNN - 1) {
    unsigned orf = K[0], anf = K[0];
#pragma unroll
    for (int s = 1; s < 32; ++s) { orf |= K[s]; anf &= K[s]; }
#pragma unroll
    for (int xm = 32; xm >= 1; xm >>= 1) {
      orf |= __shfl_xor(orf, xm);
      anf &= __shfl_xor(anf, xm);
    }
    unsigned Vf = orf ^ anf;
    P = anf & ~Vf;
    need = KNN;
    for (int b = 31; b >= 0; --b) {
      unsigned bit = 1u << b;
      if (!(Vf & bit)) continue;
      unsigned hm = 0xFFFFFFFFu << b;
      unsigned Pb = (P & hm) | bit;
      int c = 0;
#pragma unroll
      for (int s = 0; s < 32; ++s) c += (int)__popcll(__ballot((K[s] & hm) == Pb));
      if (c >= need) P |= bit;
      else need -= c;
    }
  }
  int base = 0;
  unsigned eqmask = 0;
#pragma unroll
  for (int s = 0; s < 32; ++s) {
    bool take = K[s] > P;
    unsigned long long bal = __ballot(take);
    if (take) {
      int pos = base + (int)__popcll(bal & ((1ull << lane) - 1ull));
      orow[pos] = midx<MODE>(s, lane);
    }
    base += (int)__popcll(bal);
    if (K[s] == P) eqmask |= (1u << s);
  }
  int rem = KNN - base;
  for (int it = 0; it < rem; ++it) {
    unsigned mym = 0xFFFFFFFFu;
    if (eqmask) {
      int s = __ffs(eqmask) - 1;        // per-lane smallest m (m increases with s)
      mym = (unsigned)midx<MODE>(s, lane);
    }
    unsigned wm = mym;
#pragma unroll
    for (int xm = 32; xm >= 1; xm >>= 1) {
      unsigned o = __shfl_xor(wm, xm);
      wm = o < wm ? o : wm;
    }
    if (mym == wm) {
      orow[base + it] = (int)wm;
      eqmask &= eqmask - 1;
    }
  }
}

// ---- knn3 body: fused pd+select for layer 1 (C=3), x+xx staged in LDS ----
static __device__ __forceinline__ void knn3_body(char* smem, const float* __restrict__ xf,
                                                 const float* __restrict__ xxb,
                                                 int* __restrict__ idxout, int b, int nblk) {
  float* xs = (float*)smem;          // [3*NPTS]
  float* xxs = xs + 3 * NPTS;        // [NPTS]
  int tid = threadIdx.x, wave = tid >> 6, lane = tid & 63;
  const float* xb = xf + (long)b * 3 * NPTS;
  for (int i = tid; i < 3 * NPTS; i += 256) xs[i] = xb[i];
  for (int i = tid; i < NPTS; i += 256) xxs[i] = xxb[(b << 11) + i];
  __syncthreads();
  int n = nblk * 4 + wave;
  float q0 = xs[n], q1 = xs[NPTS + n], q2 = xs[2 * NPTS + n];
  float xxn = xxs[n];
  unsigned K[32];
#pragma unroll
  for (int s = 0; s < 32; ++s) {
    int m = s * 64 + lane;
    float d = 0.f;
    d = fmaf(q0, xs[m], d);
    d = fmaf(q1, xs[NPTS + m], d);
    d = fmaf(q2, xs[2 * NPTS + m], d);
    float pdv = (-xxn - (-2.f * d)) - xxs[m];
    K[s] = ordkey(pdv);
  }
  select_from_K<1>(K, lane, idxout + (((b << 11) | n) * KNN));
}

// ---- pd body: 64x64 symmetric tile (triangular id), LDS Ts mirror, NT key stores ----
template <int C>
static __device__ __forceinline__ void pd_body(char* smem, const float* __restrict__ x,
                                               long bstride, const float* __restrict__ xx,
                                               unsigned* __restrict__ keys, int t, int bb) {
  constexpr int KT = (C < 16) ? C : 16;
  float* At = (float*)smem;                  // [KT][64]
  float* Bt = At + KT * 64;                  // [KT][64]
  unsigned* Ts = (unsigned*)(Bt + KT * 64);  // [64][68]
  int tj = (int)((sqrtf(8.f * (float)t + 1.f) - 1.f) * 0.5f);
  while ((tj + 1) * (tj + 2) / 2 <= t) tj++;
  while (tj * (tj + 1) / 2 > t) tj--;
  int ti = t - tj * (tj + 1) / 2;            // ti <= tj
  int n0 = ti * 64, m0 = tj * 64;
  int tid = threadIdx.x, tx = tid & 15, ty = tid >> 4;
  const float* xb = x + (long)bb * bstride;
  float acc[4][4] = {};
  for (int k0 = 0; k0 < C; k0 += KT) {
    for (int lin = tid; lin < KT * 64; lin += 256) {
      int r = lin >> 6, col = lin & 63;
      At[r * 64 + col] = xb[(long)(k0 + r) * NPTS + n0 + col];
      Bt[r * 64 + col] = xb[(long)(k0 + r) * NPTS + m0 + col];
    }
    __syncthreads();
#pragma unroll
    for (int kc = 0; kc < KT; ++kc) {
      float4 av = *(const float4*)&At[kc * 64 + ty * 4];
      float4 bv = *(const float4*)&Bt[kc * 64 + tx * 4];
      acc[0][0] = fmaf(av.x, bv.x, acc[0][0]); acc[0][1] = fmaf(av.x, bv.y, acc[0][1]);
      acc[0][2] = fmaf(av.x, bv.z, acc[0][2]); acc[0][3] = fmaf(av.x, bv.w, acc[0][3]);
      acc[1][0] = fmaf(av.y, bv.x, acc[1][0]); acc[1][1] = fmaf(av.y, bv.y, acc[1][1]);
      acc[1][2] = fmaf(av.y, bv.z, acc[1][2]); acc[1][3] = fmaf(av.y, bv.w, acc[1][3]);
      acc[2][0] = fmaf(av.z, bv.x, acc[2][0]); acc[2][1] = fmaf(av.z, bv.y, acc[2][1]);
      acc[2][2] = fmaf(av.z, bv.z, acc[2][2]); acc[2][3] = fmaf(av.z, bv.w, acc[2][3]);
      acc[3][0] = fmaf(av.w, bv.x, acc[3][0]); acc[3][1] = fmaf(av.w, bv.y, acc[3][1]);
      acc[3][2] = fmaf(av.w, bv.z, acc[3][2]); acc[3][3] = fmaf(av.w, bv.w, acc[3][3]);
    }
    __syncthreads();
  }
  const float* xxq = xx + (long)bb * NPTS;
  float4 xxm = *(const float4*)&xxq[m0 + tx * 4];
  unsigned* kb = keys + ((long)bb << 22);
  unsigned ok[4][4];
#pragma unroll
  for (int i = 0; i < 4; ++i) {
    float xxn = xxq[n0 + ty * 4 + i];
    ok[i][0] = ordkey((-xxn - (-2.f * acc[i][0])) - xxm.x);
    ok[i][1] = ordkey((-xxn - (-2.f * acc[i][1])) - xxm.y);
    ok[i][2] = ordkey((-xxn - (-2.f * acc[i][2])) - xxm.z);
    ok[i][3] = ordkey((-xxn - (-2.f * acc[i][3])) - xxm.w);
    uint4v o = {ok[i][0], ok[i][1], ok[i][2], ok[i][3]};
    __builtin_nontemporal_store(o, (uint4v*)&kb[(long)(n0 + ty * 4 + i) * NPTS + m0 + tx * 4]);
  }
  if (ti != tj) {
#pragma unroll
    for (int i = 0; i < 4; ++i)
#pragma unroll
      for (int j = 0; j < 4; ++j) Ts[(tx * 4 + j) * 68 + ty * 4 + i] = ok[i][j];
    __syncthreads();
#pragma unroll
    for (int i = 0; i < 4; ++i) {
      uint4v w = *(const uint4v*)&Ts[(ty * 4 + i) * 68 + tx * 4];
      __builtin_nontemporal_store(w, (uint4v*)&kb[(long)(m0 + ty * 4 + i) * NPTS + n0 + tx * 4]);
    }
  }
}

// ---- yzt body: point-major GEMM, yt[b][m][o], zt[b][m][o] ----
template <int C>
static __device__ __forceinline__ void yzt_body(char* smem, const float* __restrict__ x,
                                                long bstride, const float* __restrict__ W, int O,
                                                float* __restrict__ yt, float* __restrict__ zt,
                                                int b, int m0, int o0) {
  constexpr int KT = (C < 16) ? C : 16;
  float* Xs = (float*)smem;        // [KT][64]
  float* Wy = Xs + KT * 64;        // [KT][64]
  float* Wp = Wy + KT * 64;        // [KT][64]
  int tid = threadIdx.x, tx = tid & 15, ty = tid >> 4;
  const float* xb = x + (long)b * bstride;
  const int twoC = 2 * C;
  float accy[4][4] = {}, accp[4][4] = {};
  for (int k0 = 0; k0 < C; k0 += KT) {
    for (int lin = tid; lin < KT * 64; lin += 256) {
      int r = lin >> 6, col = lin & 63;
      Xs[r * 64 + col] = xb[(long)(k0 + r) * NPTS + m0 + col];
      float wy = W[(o0 + col) * twoC + k0 + r];
      Wy[r * 64 + col] = wy;
      Wp[r * 64 + col] = W[(o0 + col) * twoC + C + k0 + r] - wy;
    }
    __syncthreads();
#pragma unroll
    for (int kc = 0; kc < KT; ++kc) {
      float4 wv = *(const float4*)&Wy[kc * 64 + tx * 4];
      float4 pv = *(const float4*)&Wp[kc * 64 + tx * 4];
      float xm[4];
      xm[0] = Xs[kc * 64 + ty * 4 + 0]; xm[1] = Xs[kc * 64 + ty * 4 + 1];
      xm[2] = Xs[kc * 64 + ty * 4 + 2]; xm[3] = Xs[kc * 64 + ty * 4 + 3];
#pragma unroll
      for (int i = 0; i < 4; ++i) {
        accy[i][0] = fmaf(xm[i], wv.x, accy[i][0]);
        accy[i][1] = fmaf(xm[i], wv.y, accy[i][1]);
        accy[i][2] = fmaf(xm[i], wv.z, accy[i][2]);
        accy[i][3] = fmaf(xm[i], wv.w, accy[i][3]);
        accp[i][0] = fmaf(xm[i], pv.x, accp[i][0]);
        accp[i][1] = fmaf(xm[i], pv.y, accp[i][1]);
        accp[i][2] = fmaf(xm[i], pv.z, accp[i][2]);
        accp[i][3] = fmaf(xm[i], pv.w, accp[i][3]);
      }
    }
    __syncthreads();
  }
#pragma unroll
  for (int i = 0; i < 4; ++i) {
    long base = ((long)b * NPTS + m0 + ty * 4 + i) * O + o0 + tx * 4;
    *(float4*)&yt[base] = make_float4(accy[i][0], accy[i][1], accy[i][2], accy[i][3]);
    *(float4*)&zt[base] = make_float4(accp[i][0], accp[i][1], accp[i][2], accp[i][3]);
  }
}

// ---- select body (keys layout), NT loads ----
static __device__ __forceinline__ void select_body(const unsigned* __restrict__ keys,
                                                   int* __restrict__ idxout, int q) {
  int lane = threadIdx.x & 63;
  int bloc = q >> 11, n = q & 2047;
  const uint4v* rp = (const uint4v*)(keys + ((long)((bloc << 11) | n) << 11));
  unsigned K[32];
#pragma unroll
  for (int t = 0; t < 8; ++t) {
    uint4v kk = __builtin_nontemporal_load(rp + t * 64 + lane);
    K[4 * t + 0] = kk.x; K[4 * t + 1] = kk.y; K[4 * t + 2] = kk.z; K[4 * t + 3] = kk.w;
  }
  select_from_K<0>(K, lane, idxout + ((bloc << 11) | n) * KNN);
}

// fused select || yzt, INTERLEAVED: every K-th block (c<nyzt) is yzt, rest select.
template <int C, int O64>
__global__ __launch_bounds__(256) void selyzt_kernel(const unsigned* __restrict__ keys,
                                                     int* __restrict__ idxout,
                                                     const float* __restrict__ x, long bstride,
                                                     const float* __restrict__ W,
                                                     float* __restrict__ yt,
                                                     float* __restrict__ zt, int K, int nyzt) {
  constexpr int KT = (C < 16) ? C : 16;
  __shared__ __align__(16) char smem[(size_t)KT * 64 * 3 * 4];
  int bid = blockIdx.x;
  int c = bid / K, r = bid - c * K;
  if (r == 0 && c < nyzt) {
    int rem = c;                         // o64 * (32*NB) + my*NB + b
    int b = rem % NB; rem /= NB;
    int m0 = (rem % 32) * 64; rem /= 32;
    int o0 = rem * 64;
    yzt_body<C>(smem, x, bstride, W, O64 * 64, yt, zt, b, m0, o0);
  } else {
    int sid = (c < nyzt) ? (c * (K - 1) + r - 1) : (bid - nyzt);
    int wave = threadIdx.x >> 6;
    select_body(keys, idxout, sid * 4 + wave);
  }
}

// fused knn3 || yzt<3>, INTERLEAVED (layer 1)
__global__ __launch_bounds__(256) void knn3yzt_kernel(const float* __restrict__ xf,
                                                      const float* __restrict__ xxb,
                                                      int* __restrict__ idxout,
                                                      const float* __restrict__ W1,
                                                      float* __restrict__ yt,
                                                      float* __restrict__ zt, int K, int nyzt) {
  __shared__ __align__(16) char smem[4 * NPTS * 4];   // 32 KB (knn3 arena; yzt<3> uses prefix)
  int bid = blockIdx.x;
  int c = bid / K, r = bid - c * K;
  if (r == 0 && c < nyzt) {
    int b = c % NB;
    int m0 = ((c / NB) % 32) * 64;
    yzt_body<3>(smem, xf, 3L * NPTS, W1, 64, yt, zt, b, m0, 0);
  } else {
    int sid = (c < nyzt) ? (c * (K - 1) + r - 1) : (bid - nyzt);
    knn3_body(smem, xf, xxb, idxout, sid >> 9, sid & 511);
  }
}

// standalone kernels (fallback path)
__global__ __launch_bounds__(256) void select_kernel(const unsigned* __restrict__ keys,
                                                     int* __restrict__ idxout) {
  int wave = threadIdx.x >> 6;
  select_body(keys, idxout, blockIdx.x * 4 + wave);
}

template <int C>
__global__ __launch_bounds__(256) void pdgemmsym_kernel(const float* __restrict__ x, long bstride,
                                                        const float* __restrict__ xx,
                                                        unsigned* __restrict__ keys) {
  constexpr int KT = (C < 16) ? C : 16;
  constexpr size_t SM = (size_t)KT * 64 * 2 * 4 + 64 * 68 * 4;
  __shared__ __align__(16) char smem[SM];
  pd_body<C>(smem, x, bstride, xx, keys, blockIdx.x, blockIdx.y);
}

template <int C>
__global__ __launch_bounds__(256) void yzt_kernel(const float* __restrict__ x, long bstride,
                                                  const float* __restrict__ W, int O,
                                                  float* __restrict__ yt, float* __restrict__ zt) {
  constexpr int KT = (C < 16) ? C : 16;
  constexpr size_t SM = (size_t)KT * 64 * 3 * 4;
  __shared__ __align__(16) char smem[SM];
  yzt_body<C>(smem, x, bstride, W, O, yt, zt, blockIdx.z, blockIdx.y * 64, blockIdx.x * 64);
}

// gmaxt: one wave per query n; emits xx for next layer + bf16 point-major cat copy
template <int RO>
__global__ __launch_bounds__(256) void gmaxt_kernel(const float* __restrict__ yt,
                                                    const float* __restrict__ zt,
                                                    const int* __restrict__ idx,
                                                    const float* __restrict__ g,
                                                    const float* __restrict__ bb,
                                                    float* __restrict__ out, long obstride,
                                                    float* __restrict__ xxout,
                                                    __hip_bfloat16* __restrict__ catbf, int loff) {
  constexpr int O = RO * 64;
  int wave = threadIdx.x >> 6, lane = threadIdx.x & 63;
  int n = blockIdx.x * 4 + wave, b = blockIdx.y;
  int jreg = idx[((b << 11) + n) * KNN + (lane & 31)];
  int obase = lane * RO;
  float gs[RO], bs[RO], zr[RO], acc[RO];
  loadv(zt + ((long)(b << 11) + n) * O + obase, zr);
#pragma unroll
  for (int r = 0; r < RO; ++r) {
    gs[r] = g[obase + r] * ISQ;
    bs[r] = bb[obase + r];
    acc[r] = -INFINITY;
  }
  const float* yb = yt + ((long)(b << 11)) * O + obase;
#pragma unroll
  for (int k = 0; k < KNN; ++k) {
    int j = __shfl(jreg, k);
    float yv[RO];
    loadv(yb + (long)j * O, yv);
#pragma unroll
    for (int r = 0; r < RO; ++r) {
      float v = fmaf(gs[r], yv[r] + zr[r], bs[r]);
      v = v >= 0.f ? v : 0.2f * v;
      acc[r] = fmaxf(acc[r], v);
    }
  }
  float* op = out + (long)b * obstride + (long)obase * NPTS + n;
#pragma unroll
  for (int r = 0; r < RO; ++r) op[(long)r * NPTS] = acc[r];
  __hip_bfloat16* cb = catbf + ((long)(b << 11) + n) * 512 + loff + obase;
#pragma unroll
  for (int r = 0; r < RO; ++r) cb[r] = __float2bfloat16(acc[r]);
  if (xxout) {
    float ss = 0.f;
#pragma unroll
    for (int r = 0; r < RO; ++r) ss = fmaf(acc[r], acc[r], ss);
    ss = wave_red_sum(ss);
    if (lane == 0) xxout[(b << 11) + n] = ss;
  }
}

// MFMA W5 GEMM + BN + leaky + 64n partial max. LDS-staged B, double-buffered.
__global__ __launch_bounds__(256) void gemm5m_kernel(const __hip_bfloat16* __restrict__ catbf,
                                                     const __hip_bfloat16* __restrict__ w5bf,
                                                     const float* __restrict__ g5,
                                                     const float* __restrict__ b5,
                                                     float* __restrict__ pmax) {
  __shared__ __align__(16) short Bs[2][8 * 64 * 8];
  int b = blockIdx.z, po0 = blockIdx.y * 128, n0 = blockIdx.x * 64;
  int wave = threadIdx.x >> 6, lane = threadIdx.x & 63;
  int quad = lane >> 4, l15 = lane & 15;
  const short* cbase = (const short*)catbf + ((long)(b << 11) + n0) * 512;
  const short* abase0 = (const short*)w5bf + (long)(po0 + wave * 32 + l15) * 512 + quad * 8;
  const short* abase1 = abase0 + 16 * 512;
  const short* bsrc0 = cbase + (long)lane * 512 + (2 * wave + 0) * 8;
  const short* bsrc1 = cbase + (long)lane * 512 + (2 * wave + 1) * 8;
  short* bdst0 = &Bs[0][((2 * wave + 0) * 64 + lane) * 8];
  short* bdst1 = &Bs[0][((2 * wave + 1) * 64 + lane) * 8];
  const int bufstride = 8 * 64 * 8;

  short8v Br[2][2], Ar[2][2][2];
  f32x4 acc[2][4] = {};

  Br[0][0] = *(const short8v*)(bsrc0);
  Br[0][1] = *(const short8v*)(bsrc1);
#pragma unroll
  for (int h = 0; h < 2; ++h)
#pragma unroll
    for (int j = 0; j < 2; ++j)
      Ar[0][h][j] = *(const short8v*)((h ? abase1 : abase0) + j * 32);
  *(short8v*)bdst0 = Br[0][0];
  *(short8v*)bdst1 = Br[0][1];
  Br[1][0] = *(const short8v*)(bsrc0 + 64);
  Br[1][1] = *(const short8v*)(bsrc1 + 64);
#pragma unroll
  for (int h = 0; h < 2; ++h)
#pragma unroll
    for (int j = 0; j < 2; ++j)
      Ar[1][h][j] = *(const short8v*)((h ? abase1 : abase0) + 64 + j * 32);
  __syncthreads();

  for (int it = 0; it < 8; ++it) {
    int cur = it & 1;
    const short* lb = &Bs[cur][0];
#pragma unroll
    for (int j = 0; j < 2; ++j) {
#pragma unroll
      for (int nt = 0; nt < 4; ++nt) {
        short8v bf = *(const short8v*)(lb + ((j * 4 + quad) * 64 + nt * 16 + l15) * 8);
        acc[0][nt] = __builtin_amdgcn_mfma_f32_16x16x32_bf16(Ar[cur][0][j], bf, acc[0][nt], 0, 0, 0);
        acc[1][nt] = __builtin_amdgcn_mfma_f32_16x16x32_bf16(Ar[cur][1][j], bf, acc[1][nt], 0, 0, 0);
      }
    }
    if (it < 7) {
      if (it < 6) {
        int ks = (it + 2) * 64;
        Br[cur][0] = *(const short8v*)(bsrc0 + ks);
        Br[cur][1] = *(const short8v*)(bsrc1 + ks);
#pragma unroll
        for (int h = 0; h < 2; ++h)
#pragma unroll
          for (int j = 0; j < 2; ++j)
            Ar[cur][h][j] = *(const short8v*)((h ? abase1 : abase0) + ks + j * 32);
      }
      int nb = cur ^ 1;
      *(short8v*)(bdst0 + nb * bufstride) = Br[nb][0];
      *(short8v*)(bdst1 + nb * bufstride) = Br[nb][1];
      __syncthreads();
    }
  }

#pragma unroll
  for (int h = 0; h < 2; ++h) {
#pragma unroll
    for (int r = 0; r < 4; ++r) {
      int po = po0 + wave * 32 + h * 16 + quad * 4 + r;
      float sc = g5[po] * ISQ;
      float bi = b5[po];
      float mx = -INFINITY;
#pragma unroll
      for (int nt = 0; nt < 4; ++nt) {
        float v = fmaf(sc, acc[h][nt][r], bi);
        v = v >= 0.f ? v : 0.2f * v;
        mx = fmaxf(mx, v);
      }
#pragma unroll
      for (int xm = 1; xm < 16; xm <<= 1) mx = fmaxf(mx, __shfl_xor(mx, xm));
      if (l15 == 0) pmax[(long)(b * 1024 + po) * 32 + blockIdx.x] = mx;
    }
  }
}

// merged: blocks 0..15 -> global-max reduce of pmax into v; blocks 16..17 -> lf/nf
__global__ __launch_bounds__(256) void redlfnf_kernel(const float* __restrict__ pmax,
                                                      const float* __restrict__ l,
                                                      const float* __restrict__ nn,
                                                      const float* __restrict__ W6,
                                                      const float* __restrict__ g6,
                                                      const float* __restrict__ b6,
                                                      const float* __restrict__ W7,
                                                      const float* __restrict__ g7,
                                                      const float* __restrict__ b7,
                                                      float* __restrict__ v) {
  if (blockIdx.x < 16) {
    int t = blockIdx.x * 256 + threadIdx.x;   // b*1024 + po  (4096)
    float mx = -INFINITY;
#pragma unroll
    for (int j = 0; j < 32; ++j) mx = fmaxf(mx, pmax[(long)t * 32 + j]);
    int b = t >> 10, po = t & 1023;
    v[b * 1152 + po] = mx;
  } else {
    int idx = (blockIdx.x - 16) * 256 + threadIdx.x;  // 512 work items
    int b = idx >> 7, t = idx & 127;
    if (t < 64) {
      float s = 0.f;
#pragma unroll
      for (int c = 0; c < 5; ++c) s = fmaf(W6[t * 5 + c], l[b * 5 + c], s);
      float val = fmaf(g6[t] * ISQ, s, b6[t]);
      v[b * 1152 + 1024 + t] = val >= 0.f ? val : 0.2f * val;
    } else {
      int o = t - 64;
      float s = 0.f;
#pragma unroll
      for (int c = 0; c < 7; ++c) s = fmaf(W7[o * 7 + c], nn[b * 7 + c], s);
      float val = fmaf(g7[o] * ISQ, s, b7[o]);
      v[b * 1152 + 1088 + o] = val >= 0.f ? val : 0.2f * val;
    }
  }
}

// one wave per output row; lane-strided dot + shuffle reduce
__global__ __launch_bounds__(256) void head1_kernel(const float* __restrict__ v,
                                                    const float* __restrict__ L1,
                                                    const float* __restrict__ g8,
                                                    const float* __restrict__ b8,
                                                    float* __restrict__ v1) {
  int wave = threadIdx.x >> 6, lane = threadIdx.x & 63;
  int t = blockIdx.x * 4 + wave;   // b*512 + o  (2048)
  int b = t >> 9, o = t & 511;
  const float* vb = v + b * 1152;
  const float* wr = L1 + (long)o * 1152;
  float s = 0.f;
#pragma unroll
  for (int c = lane; c < 1152; c += 64) s = fmaf(wr[c], vb[c], s);
  s = wave_red_sum(s);
  if (lane == 0) {
    float val = fmaf(g8[o] * ISQ, s, b8[o]);
    v1[t] = fmaxf(val, 0.f);
  }
}

__global__ __launch_bounds__(256) void head2_kernel(const float* __restrict__ v1,
                                                    const float* __restrict__ L2,
                                                    const float* __restrict__ L2b,
                                                    const float* __restrict__ g9,
                                                    const float* __restrict__ b9,
                                                    float* __restrict__ v2) {
  int wave = threadIdx.x >> 6, lane = threadIdx.x & 63;
  int t = blockIdx.x * 4 + wave;   // b*256 + o  (1024)
  int b = t >> 8, o = t & 255;
  const float* vb = v1 + b * 512;
  const float* wr = L2 + (long)o * 512;
  float s = 0.f;
#pragma unroll
  for (int c = lane; c < 512; c += 64) s = fmaf(wr[c], vb[c], s);
  s = wave_red_sum(s);
  if (lane == 0) {
    float sv = s + L2b[o];
    float val = fmaf(g9[o] * ISQ, sv, b9[o]);
    v2[t] = fmaxf(val, 0.f);
  }
}

__global__ __launch_bounds__(256) void head3_kernel(const float* __restrict__ v2,
                                                    const float* __restrict__ L3,
                                                    const float* __restrict__ L3b,
                                                    void* __restrict__ out,
                                                    const int* __restrict__ flag) {
  int wave = threadIdx.x >> 6, lane = threadIdx.x & 63;
  int t = blockIdx.x * 4 + wave;   // b*28 + o  (112)
  if (t >= 112) return;
  int b = t / 28, o = t % 28;
  const float* vb = v2 + b * 256;
  const float* wr = L3 + o * 256;
  float s = 0.f;
#pragma unroll
  for (int c = lane; c < 256; c += 64) s = fmaf(wr[c], vb[c], s);
  s = wave_red_sum(s);
  if (lane == 0) {
    float sv = s + L3b[o];
    if (flag[0]) ((__hip_bfloat16*)out)[t] = __float2bfloat16(sv);
    else         ((float*)out)[t] = sv;
  }
}

extern "C" void kernel_launch(void* const* d_in, const int* in_sizes, int n_in,
                              void* d_out, int out_size, void* d_ws, size_t ws_size,
                              hipStream_t stream) {
  CvtArgs ca;
  int off[NIN + 1];
  off[0] = 0;
  for (int i = 0; i < NIN; ++i) {
    ca.src[i] = d_in[i];
    off[i + 1] = off[i] + in_sizes[i];
    ca.off[i] = off[i];
  }
  ca.off[NIN] = off[NIN];
  const int total = off[NIN];

  int* flag = (int*)d_ws;
  float* fin = (float*)((char*)d_ws + 64);
  const float* xf  = fin + off[0];
  const float* lf  = fin + off[1];
  const float* nf  = fin + off[2];
  const float* W1f = fin + off[3];  const float* g1f = fin + off[4];  const float* b1f = fin + off[5];
  const float* W2f = fin + off[6];  const float* g2f = fin + off[7];  const float* b2f_ = fin + off[8];
  const float* W3f = fin + off[9];  const float* g3f = fin + off[10]; const float* b3f = fin + off[11];
  const float* W4f = fin + off[12]; const float* g4f = fin + off[13]; const float* b4f = fin + off[14];
  const float* g5f = fin + off[16]; const float* b5f = fin + off[17];
  const float* W6f = fin + off[18]; const float* g6f = fin + off[19]; const float* b6f = fin + off[20];
  const float* W7f = fin + off[21]; const float* g7f = fin + off[22]; const float* b7f = fin + off[23];
  const float* L1f = fin + off[24]; const float* g8f = fin + off[25]; const float* b8f = fin + off[26];
  const float* L2f = fin + off[27]; const float* L2bf = fin + off[28];
  const float* g9f = fin + off[29]; const float* b9f = fin + off[30];
  const float* L3f = fin + off[31]; const float* L3bf = fin + off[32];

  float* p = fin + ((total + 15) & ~15);
  float* cat  = p;                               // 4*512*2048 (fp32, channel-major)
  float* yb   = cat + 4 * 512 * NPTS;            // 4*2048*256 (point-major)
  float* zb   = yb + 4 * 256 * NPTS;             // 4*2048*256 (point-major)
  float* xxb  = zb + 4 * 256 * NPTS;             // 4*2048
  int*   idxb = (int*)(xxb + 4 * NPTS);          // 4*2048*32
  float* pmax = (float*)(idxb + 4 * NPTS * KNN); // 4*1024*32
  float* vb   = pmax + 4 * 1024 * 32;            // 4*1152
  float* v1b  = vb + 4 * 1152;                   // 4*512
  float* v2b  = v1b + 4 * 512;                   // 4*256
  __hip_bfloat16* w5bf  = (__hip_bfloat16*)(v2b + 4 * 256);           // 1024*512 bf16
  __hip_bfloat16* catbf = w5bf + 1024 * 512;                          // 4*2048*512 bf16
  unsigned* keys_tail = (unsigned*)(catbf + (size_t)4 * NPTS * 512);

  size_t need_full = (size_t)((char*)(keys_tail + (size_t)NB * NPTS * NPTS) - (char*)d_ws);
  int bpass = (ws_size >= need_full) ? NB : 1;
  unsigned* keys = (bpass == NB) ? keys_tail : (unsigned*)yb;

  const long bst1 = 3L * NPTS;
  const long bstc = 512L * NPTS;
  const int NTRI = 32 * 33 / 2;   // 528 triangular 64x64 tiles
  const int nb1 = (total + 255) / 256;
  const int NSEL = NB * 512;      // 2048 select blocks (4 rows each)

  detect_kernel<<<1, 64, 0, stream>>>((const unsigned short*)d_in[0], flag);
  cvt_all_kernel<<<nb1 + 2048 + 32, 256, 0, stream>>>(ca, fin, total, nb1, w5bf, xxb, flag);

  // ---- layer 1: C=3, O=64 — fused in-LDS knn || yzt (interleaved)
  {
    int nyzt = 32 * NB;                         // 128
    int tot = NSEL + nyzt;                      // 2176
    knn3yzt_kernel<<<tot, 256, 0, stream>>>(xf, xxb, idxb, W1f, yb, zb, tot / nyzt, nyzt);
  }
  gmaxt_kernel<1><<<dim3(512, NB), 256, 0, stream>>>(yb, zb, idxb, g1f, b1f, cat, bstc, xxb, catbf, 0);

  // ---- layer 2: C=64, O=64
  if (bpass == NB) {
    pdgemmsym_kernel<64><<<dim3(NTRI, NB), 256, 0, stream>>>(cat, bstc, xxb, keys);
    int nyzt = 1 * 32 * NB, tot = NSEL + nyzt;
    selyzt_kernel<64, 1><<<tot, 256, 0, stream>>>(keys, idxb, cat, bstc, W2f, yb, zb, tot / nyzt, nyzt);
  } else {
    for (int b0 = 0; b0 < NB; b0 += bpass) {
      pdgemmsym_kernel<64><<<dim3(NTRI, bpass), 256, 0, stream>>>(cat + b0 * bstc, bstc, xxb + b0 * NPTS, keys);
      select_kernel<<<512 * bpass, 256, 0, stream>>>(keys, idxb + (long)b0 * NPTS * KNN);
    }
    yzt_kernel<64><<<dim3(1, 32, NB), 256, 0, stream>>>(cat, bstc, W2f, 64, yb, zb);
  }
  gmaxt_kernel<1><<<dim3(512, NB), 256, 0, stream>>>(yb, zb, idxb, g2f, b2f_, cat + 64L * NPTS, bstc, xxb, catbf, 64);

  // ---- layer 3: C=64, O=128
  if (bpass == NB) {
    pdgemmsym_kernel<64><<<dim3(NTRI, NB), 256, 0, stream>>>(cat + 64L * NPTS, bstc, xxb, keys);
    int nyzt = 2 * 32 * NB, tot = NSEL + nyzt;
    selyzt_kernel<64, 2><<<tot, 256, 0, stream>>>(keys, idxb, cat + 64L * NPTS, bstc, W3f, yb, zb, tot / nyzt, nyzt);
  } else {
    for (int b0 = 0; b0 < NB; b0 += bpass) {
      pdgemmsym_kernel<64><<<dim3(NTRI, bpass), 256, 0, stream>>>(cat + 64L * NPTS + b0 * bstc, bstc, xxb + b0 * NPTS, keys);
      select_kernel<<<512 * bpass, 256, 0, stream>>>(keys, idxb + (long)b0 * NPTS * KNN);
    }
    yzt_kernel<64><<<dim3(2, 32, NB), 256, 0, stream>>>(cat + 64L * NPTS, bstc, W3f, 128, yb, zb);
  }
  gmaxt_kernel<2><<<dim3(512, NB), 256, 0, stream>>>(yb, zb, idxb, g3f, b3f, cat + 128L * NPTS, bstc, xxb, catbf, 128);

  // ---- layer 4: C=128, O=256
  if (bpass == NB) {
    pdgemmsym_kernel<128><<<dim3(NTRI, NB), 256, 0, stream>>>(cat + 128L * NPTS, bstc, xxb, keys);
    int nyzt = 4 * 32 * NB, tot = NSEL + nyzt;
    selyzt_kernel<128, 4><<<tot, 256, 0, stream>>>(keys, idxb, cat + 128L * NPTS, bstc, W4f, yb, zb, tot / nyzt, nyzt);
  } else {
    for (int b0 = 0; b0 < NB; b0 += bpass) {
      pdgemmsym_kernel<128><<<dim3(NTRI, bpass), 256, 0, stream>>>(cat + 128L * NPTS + b0 * bstc, bstc, xxb + b0 * NPTS, keys);
      select_kernel<<<512 * bpass, 256, 0, stream>>>(keys, idxb + (long)b0 * NPTS * KNN);
    }
    yzt_kernel<128><<<dim3(4, 32, NB), 256, 0, stream>>>(cat + 128L * NPTS, bstc, W4f, 256, yb, zb);
  }
  gmaxt_kernel<4><<<dim3(512, NB), 256, 0, stream>>>(yb, zb, idxb, g4f, b4f, cat + 256L * NPTS, bstc, (float*)nullptr, catbf, 256);

  // ---- conv5 (bf16 MFMA, LDS-staged B, double-buffered) + BN + leaky + global max
  gemm5m_kernel<<<dim3(32, 8, NB), 256, 0, stream>>>(catbf, w5bf, g5f, b5f, pmax);
  redlfnf_kernel<<<18, 256, 0, stream>>>(pmax, lf, nf, W6f, g6f, b6f, W7f, g7f, b7f, vb);

  head1_kernel<<<512, 256, 0, stream>>>(vb, L1f, g8f, b8f, v1b);
  head2_kernel<<<256, 256, 0, stream>>>(v1b, L2f, L2bf, g9f, b9f, v2b);
  head3_kernel<<<28, 256, 0, stream>>>(v2b, L3f, L3bf, d_out, flag);
}